// Round 9
// baseline (1357.487 us; speedup 1.0000x reference)
//
#include <hip/hip_runtime.h>

#define N_NODES 50000
#define N_EDGES 640000
#define N_GRAPH 1024
#define D 128
#define RD 200

typedef __attribute__((ext_vector_type(4))) float f32x4;
typedef __attribute__((ext_vector_type(8))) float f32x8;
typedef __attribute__((ext_vector_type(2))) _Float16 half2v;
typedef __attribute__((ext_vector_type(4))) _Float16 half4;
typedef __attribute__((ext_vector_type(8))) _Float16 half8;

static __device__ __forceinline__ int lbound(const int* a, int n, int v) {
  int lo = 0, hi = n;
  while (lo < hi) { int m = (lo + hi) >> 1; if (a[m] < v) lo = m + 1; else hi = m; }
  return lo;
}

// ---- prep: weights -> fp16 fragment order; zero deg + steal counters ----
__global__ void k_prep(const float* __restrict__ w0, const float* __restrict__ w1,
                       const float* __restrict__ w2, const float* __restrict__ w3,
                       const float* __restrict__ mw1, const float* __restrict__ mw2,
                       _Float16* __restrict__ cWf,   // [4][32*64*8]
                       _Float16* __restrict__ W1f,   // [352*64*8]
                       _Float16* __restrict__ W2f,   // [256*64*8]
                       int* __restrict__ deg, int* __restrict__ cnt) {
  int t = blockIdx.x * 256 + threadIdx.x;  // 0..65535
  if (t < N_NODES) deg[t] = 0;
  if (t == 0) { cnt[0] = 0; cnt[1] = 0; }
  if (t < 8192) {
    int mat = t >> 11, r = t & 2047;
    int frag = r >> 6, lane = r & 63;
    int n0 = frag >> 2, kk = frag & 3;
    int n = n0 * 16 + (lane & 15);
    int kb = (lane >> 4) * 8 + kk * 32;
    const float* W = (mat == 0) ? w0 : (mat == 1) ? w1 : (mat == 2) ? w2 : w3;
    half8 o;
#pragma unroll
    for (int j = 0; j < 8; ++j) o[j] = (_Float16)W[(kb + j) * D + n];
    *(half8*)&cWf[((size_t)mat * 2048 + r) * 8] = o;
  } else if (t < 8192 + 22528) {
    int u = t - 8192;
    int frag = u >> 6, lane = u & 63;
    int n0 = frag / 11, kk = frag % 11;
    int n = n0 * 16 + (lane & 15);
    int kb = (lane >> 4) * 8 + kk * 32;
    half8 o;
#pragma unroll
    for (int j = 0; j < 8; ++j) {
      int k = kb + j;
      o[j] = (k < 328) ? (_Float16)mw1[k * 512 + n] : (_Float16)0.f;
    }
    *(half8*)&W1f[(size_t)u * 8] = o;
  } else if (t < 8192 + 22528 + 16384) {
    int u = t - 8192 - 22528;
    int frag = u >> 6, lane = u & 63;
    int n0 = frag >> 4, kk = frag & 15;
    int n = n0 * 16 + (lane & 15);
    int kb = (lane >> 4) * 8 + kk * 32;
    half8 o;
#pragma unroll
    for (int j = 0; j < 8; ++j) o[j] = (_Float16)mw2[(kb + j) * 256 + n];
    *(half8*)&W2f[(size_t)u * 8] = o;
  }
}

// fused: atom encoder (fp16) + degree count + dst16 + edge pack
__global__ void k_atom_count(const int* __restrict__ xf, const float* __restrict__ emb,
                             _Float16* __restrict__ x16,
                             const int* __restrict__ ei, const int* __restrict__ bondf,
                             int* __restrict__ deg,
                             unsigned short* __restrict__ dst16,
                             int* __restrict__ epack) {
  if (blockIdx.x < 6250) {
    int t = blockIdx.x * 256 + threadIdx.x;  // exactly 50000*32
    int node = t >> 5, c = (t & 31) << 2;
    float a0 = 0.f, a1 = 0.f, a2 = 0.f, a3 = 0.f;
#pragma unroll
    for (int f = 0; f < 9; ++f) {
      int v = xf[node * 9 + f];
      float4 e4 = *(const float4*)&emb[(f * 64 + v) * D + c];
      a0 += e4.x; a1 += e4.y; a2 += e4.z; a3 += e4.w;
    }
    half4 o;
    o.x = (_Float16)a0; o.y = (_Float16)a1; o.z = (_Float16)a2; o.w = (_Float16)a3;
    *(half4*)&x16[(size_t)node * D + c] = o;
  } else {
    int e = (blockIdx.x - 6250) * 256 + threadIdx.x;
    if (e < N_EDGES) {
      int d = ei[N_EDGES + e];
      atomicAdd(&deg[d], 1);
      dst16[e] = (unsigned short)d;
      int s = ei[e];
      int f0 = bondf[e * 3], f1 = bondf[e * 3 + 1], f2 = bondf[e * 3 + 2];
      epack[e] = s | (f0 << 16) | (f1 << 20) | (f2 << 24);
    }
  }
}

__global__ void k_scan_blocks(const int* __restrict__ deg, int* __restrict__ excl,
                              int* __restrict__ bsum) {
  __shared__ int sd[1024];
  int i = blockIdx.x * 1024 + threadIdx.x;
  int v = (i < N_NODES) ? deg[i] : 0;
  sd[threadIdx.x] = v;
  __syncthreads();
  for (int off = 1; off < 1024; off <<= 1) {
    int t = (threadIdx.x >= (unsigned)off) ? sd[threadIdx.x - off] : 0;
    __syncthreads();
    sd[threadIdx.x] += t;
    __syncthreads();
  }
  if (i < N_NODES) excl[i] = sd[threadIdx.x] - v;
  if (threadIdx.x == 1023) bsum[blockIdx.x] = sd[1023];
}

__global__ void k_scan_add(int* __restrict__ row_ptr, const int* __restrict__ bsum) {
  int off = 0;
  for (int b = 0; b < blockIdx.x; ++b) off += bsum[b];
  int i = blockIdx.x * 1024 + threadIdx.x;
  if (i < N_NODES) row_ptr[i] += off;
  if (blockIdx.x == 0 && threadIdx.x == 0) row_ptr[N_NODES] = N_EDGES;
}

// range-owned fill: block b owns dst in [b*196, b*196+196); streams dst16,
// appends matched packed edges at LDS-cursor positions (dense writes).
__global__ __launch_bounds__(256) void k_fill_range(
    const unsigned short* __restrict__ dst16, const int* __restrict__ epack,
    const int* __restrict__ row_ptr, int* __restrict__ csr1) {
  __shared__ int cur[196];
  int lo = blockIdx.x * 196;
  int hi = lo + 196; if (hi > N_NODES) hi = N_NODES;
  int n = hi - lo;
  for (int t = threadIdx.x; t < n; t += 256) cur[t] = row_ptr[lo + t];
  __syncthreads();
  for (int e = threadIdx.x; e < N_EDGES; e += 256) {
    int d = dst16[e];
    if (d >= lo && d < hi) {
      int pos = atomicAdd(&cur[d - lo], 1);
      csr1[pos] = epack[e];
    }
  }
}

// out[i] = x[i] + sum_j relu(x[src] + bond_emb_sum)
// packed csr (src|f<<16), fp16 packed math, wave work-stealing (chunk 4).
__global__ __launch_bounds__(256) void k_agg(
    const _Float16* __restrict__ x16, const int* __restrict__ row_ptr,
    const int* __restrict__ csr1, const float* __restrict__ bemb,
    _Float16* __restrict__ out, int* __restrict__ cnt) {
  __shared__ half8 sB[48 * 16];  // 12 KB fp16 bond table
  for (int t = threadIdx.x; t < 768; t += blockDim.x) {
    float4 v0 = *(const float4*)&bemb[t * 8];
    float4 v1 = *(const float4*)&bemb[t * 8 + 4];
    half8 h;
    h[0] = (_Float16)v0.x; h[1] = (_Float16)v0.y; h[2] = (_Float16)v0.z; h[3] = (_Float16)v0.w;
    h[4] = (_Float16)v1.x; h[5] = (_Float16)v1.y; h[6] = (_Float16)v1.z; h[7] = (_Float16)v1.w;
    sB[t] = h;
  }
  __syncthreads();
  int lane = threadIdx.x & 63;
  int quad = lane >> 4;
  int l15 = lane & 15;
  int c8 = l15 * 8;
  for (;;) {
    int base;
    if (lane == 0) base = atomicAdd(cnt, 4);
    base = __shfl(base, 0);
    if (base >= N_NODES) break;
    int iend = base + 4; if (iend > N_NODES) iend = N_NODES;
    for (int i = base; i < iend; ++i) {
      f32x8 ac[2];
      ac[0] = (f32x8)(0.f); ac[1] = (f32x8)(0.f);
      int e0 = row_ptr[i], e1 = row_ptr[i + 1];
      int j = e0 + quad;
#define EDGE(u, jj)                                                          \
      {                                                                      \
        unsigned ed = (unsigned)csr1[jj];                                    \
        half8 xr = *(const half8*)&x16[(size_t)(ed & 0xFFFF) * D + c8];      \
        unsigned p = ed >> 16;                                               \
        half8 m16 = (xr + sB[(p & 15) * 16 + l15]) +                         \
                    (sB[256 + ((p >> 4) & 15) * 16 + l15] +                  \
                     sB[512 + (p >> 8) * 16 + l15]);                         \
        f32x8 m = __builtin_convertvector(m16, f32x8);                       \
        _Pragma("unroll")                                                    \
        for (int tt = 0; tt < 8; ++tt) ac[u][tt] += fmaxf(m[tt], 0.f);       \
      }
      for (; j + 4 < e1; j += 8) { EDGE(0, j) EDGE(1, j + 4) }
      for (; j < e1; j += 4) EDGE(0, j)
#undef EDGE
      f32x8 acc = ac[0] + ac[1];
#pragma unroll
      for (int tt = 0; tt < 8; ++tt) {
        acc[tt] += __shfl_xor(acc[tt], 16);
        acc[tt] += __shfl_xor(acc[tt], 32);
      }
      if (quad == 0) {
        half8 sr = *(const half8*)&x16[(size_t)i * D + c8];
        f32x8 o = __builtin_convertvector(sr, f32x8) + acc;
        *(half8*)&out[(size_t)i * D + c8] = __builtin_convertvector(o, half8);
      }
    }
  }
}

// fused GINE nn: out = relu(A@W1+b1)@W2+b2 ; fp16 MFMA, W staged in LDS.
__global__ __launch_bounds__(256) void k_conv(
    const _Float16* __restrict__ A,
    const _Float16* __restrict__ W1f, const float* __restrict__ b1,
    const _Float16* __restrict__ W2f, const float* __restrict__ b2,
    _Float16* __restrict__ O16) {
  __shared__ _Float16 sW[2048 * 8];
  __shared__ _Float16 sI[128 * 136];
  int tid = threadIdx.x, w = tid >> 6, lane = tid & 63;
  int m0 = blockIdx.x * 128;
  int col16 = lane & 15, q = lane >> 4;
  for (int t = tid; t < 2048; t += 256)
    *(float4*)&sW[t * 8] = *(const float4*)&W1f[(size_t)t * 8];
  half8 afr[2][4];
#pragma unroll
  for (int f = 0; f < 2; ++f) {
    int row = m0 + w * 32 + f * 16 + col16;
    if (row >= N_NODES) row = N_NODES - 1;
    const _Float16* Ar = A + (size_t)row * D + q * 8;
#pragma unroll
    for (int kk = 0; kk < 4; ++kk) afr[f][kk] = *(const half8*)(Ar + kk * 32);
  }
  __syncthreads();
#pragma unroll
  for (int n0 = 0; n0 < 8; ++n0) {
    f32x4 a0 = {0.f, 0.f, 0.f, 0.f}, a1 = {0.f, 0.f, 0.f, 0.f};
#pragma unroll
    for (int kk = 0; kk < 4; ++kk) {
      half8 b = *(const half8*)&sW[((n0 * 4 + kk) * 64 + lane) * 8];
      a0 = __builtin_amdgcn_mfma_f32_16x16x32_f16(afr[0][kk], b, a0, 0, 0, 0);
      a1 = __builtin_amdgcn_mfma_f32_16x16x32_f16(afr[1][kk], b, a1, 0, 0, 0);
    }
    float bb = b1[n0 * 16 + col16];
#pragma unroll
    for (int r = 0; r < 4; ++r) {
      sI[(w * 32 + q * 4 + r) * 136 + n0 * 16 + col16] = (_Float16)fmaxf(a0[r] + bb, 0.f);
      sI[(w * 32 + 16 + q * 4 + r) * 136 + n0 * 16 + col16] = (_Float16)fmaxf(a1[r] + bb, 0.f);
    }
  }
  __syncthreads();
  for (int t = tid; t < 2048; t += 256)
    *(float4*)&sW[t * 8] = *(const float4*)&W2f[(size_t)t * 8];
  half8 a2[2][4];
#pragma unroll
  for (int f = 0; f < 2; ++f) {
    const _Float16* tr = &sI[(w * 32 + f * 16 + col16) * 136 + q * 8];
#pragma unroll
    for (int kk = 0; kk < 4; ++kk) a2[f][kk] = *(const half8*)(tr + kk * 32);
  }
  __syncthreads();
#pragma unroll
  for (int n0 = 0; n0 < 8; ++n0) {
    f32x4 a0 = {0.f, 0.f, 0.f, 0.f}, a1 = {0.f, 0.f, 0.f, 0.f};
#pragma unroll
    for (int kk = 0; kk < 4; ++kk) {
      half8 b = *(const half8*)&sW[((n0 * 4 + kk) * 64 + lane) * 8];
      a0 = __builtin_amdgcn_mfma_f32_16x16x32_f16(a2[0][kk], b, a0, 0, 0, 0);
      a1 = __builtin_amdgcn_mfma_f32_16x16x32_f16(a2[1][kk], b, a1, 0, 0, 0);
    }
    int col = n0 * 16 + col16;
    float bb = b2[col];
#pragma unroll
    for (int r = 0; r < 4; ++r) {
      int r0 = m0 + w * 32 + q * 4 + r;
      int r1 = r0 + 16;
      if (r0 < N_NODES) O16[(size_t)r0 * D + col] = (_Float16)(a0[r] + bb);
      if (r1 < N_NODES) O16[(size_t)r1 * D + col] = (_Float16)(a1[r] + bb);
    }
  }
}

// mean-pool per graph (fp16 input) + rdkit -> hcat16[G][352]
__global__ __launch_bounds__(256) void k_pool(
    const _Float16* __restrict__ x, const int* __restrict__ batch,
    const float* __restrict__ rdkit, _Float16* __restrict__ hcat) {
  int g = blockIdx.x * 4 + (threadIdx.x >> 6);
  if (g >= N_GRAPH) return;
  int lane = threadIdx.x & 63;
  int lo = lbound(batch, N_NODES, g);
  int hi = lbound(batch, N_NODES, g + 1);
  float a0 = 0.f, a1 = 0.f;
  for (int i = lo; i < hi; ++i) {
    half2v v = *(const half2v*)&x[(size_t)i * D + lane * 2];
    a0 += (float)v.x; a1 += (float)v.y;
  }
  float inv = 1.f / fmaxf((float)(hi - lo), 1.f);
  hcat[(size_t)g * 352 + lane * 2] = (_Float16)(a0 * inv);
  hcat[(size_t)g * 352 + lane * 2 + 1] = (_Float16)(a1 * inv);
  for (int r = lane; r < RD; r += 64)
    hcat[(size_t)g * 352 + D + r] = (_Float16)rdkit[g * RD + r];
  if (lane < 24) hcat[(size_t)g * 352 + 328 + lane] = (_Float16)0.f;
}

// fused head: h1 = relu(hcat@W1+b1) [LDS]; h2 = relu(h1@W2+b2); out = h2@W3+b3
__global__ __launch_bounds__(256) void k_mlp_head(
    const _Float16* __restrict__ A, const _Float16* __restrict__ W1f,
    const float* __restrict__ B1, const _Float16* __restrict__ W2f,
    const float* __restrict__ B2, const float* __restrict__ W3,
    const float* __restrict__ B3, float* __restrict__ out) {
  __shared__ _Float16 sH[16 * 520];
  __shared__ float sRed[4][16];
  int w = threadIdx.x >> 6, lane = threadIdx.x & 63;
  int m0 = blockIdx.x * 16;
  int col16 = lane & 15, q = lane >> 4;
  {
    const _Float16* Ar = A + (size_t)(m0 + col16) * 352 + q * 8;
    half8 afr[11];
#pragma unroll
    for (int kk = 0; kk < 11; ++kk) afr[kk] = *(const half8*)(Ar + kk * 32);
#pragma unroll
    for (int u = 0; u < 8; ++u) {
      int n0 = w * 8 + u;
      f32x4 acc = {0.f, 0.f, 0.f, 0.f};
#pragma unroll
      for (int kk = 0; kk < 11; ++kk) {
        half8 b = *(const half8*)&W1f[(size_t)((n0 * 11 + kk) * 64 + lane) * 8];
        acc = __builtin_amdgcn_mfma_f32_16x16x32_f16(afr[kk], b, acc, 0, 0, 0);
      }
      float bb = B1[n0 * 16 + col16];
#pragma unroll
      for (int r = 0; r < 4; ++r)
        sH[(q * 4 + r) * 520 + n0 * 16 + col16] = (_Float16)fmaxf(acc[r] + bb, 0.f);
    }
  }
  __syncthreads();
  half8 a2[16];
  {
    const _Float16* tr = &sH[col16 * 520 + q * 8];
#pragma unroll
    for (int kk = 0; kk < 16; ++kk) a2[kk] = *(const half8*)(tr + kk * 32);
  }
  f32x4 acc[4];
#pragma unroll
  for (int u = 0; u < 4; ++u) acc[u] = (f32x4){0.f, 0.f, 0.f, 0.f};
#pragma unroll
  for (int kk = 0; kk < 16; ++kk) {
#pragma unroll
    for (int u = 0; u < 4; ++u) {
      int n0 = w * 4 + u;
      half8 b = *(const half8*)&W2f[(size_t)((n0 * 16 + kk) * 64 + lane) * 8];
      acc[u] = __builtin_amdgcn_mfma_f32_16x16x32_f16(a2[kk], b, acc[u], 0, 0, 0);
    }
  }
  float p[4] = {0.f, 0.f, 0.f, 0.f};
#pragma unroll
  for (int u = 0; u < 4; ++u) {
    int col = (w * 4 + u) * 16 + col16;
    float bb = B2[col], w3 = W3[col];
#pragma unroll
    for (int r = 0; r < 4; ++r) p[r] += fmaxf(acc[u][r] + bb, 0.f) * w3;
  }
#pragma unroll
  for (int r = 0; r < 4; ++r) {
    p[r] += __shfl_xor(p[r], 1);
    p[r] += __shfl_xor(p[r], 2);
    p[r] += __shfl_xor(p[r], 4);
    p[r] += __shfl_xor(p[r], 8);
  }
  if (col16 == 0) {
#pragma unroll
    for (int r = 0; r < 4; ++r) sRed[w][q * 4 + r] = p[r];
  }
  __syncthreads();
  if (threadIdx.x < 16) {
    float s = sRed[0][threadIdx.x] + sRed[1][threadIdx.x] +
              sRed[2][threadIdx.x] + sRed[3][threadIdx.x];
    out[m0 + threadIdx.x] = s + B3[0];
  }
}

extern "C" void kernel_launch(void* const* d_in, const int* in_sizes, int n_in,
                              void* d_out, int out_size, void* d_ws, size_t ws_size,
                              hipStream_t stream) {
  const int* x_feat = (const int*)d_in[0];
  const int* ei = (const int*)d_in[1];
  const int* bondf = (const int*)d_in[2];
  const int* batch = (const int*)d_in[3];
  const float* rdkit = (const float*)d_in[4];
  const float* atom_emb = (const float*)d_in[5];
  const float* bond_emb = (const float*)d_in[6];
  const float* c1w1 = (const float*)d_in[7];
  const float* c1b1 = (const float*)d_in[8];
  const float* c1w2 = (const float*)d_in[9];
  const float* c1b2 = (const float*)d_in[10];
  const float* c2w1 = (const float*)d_in[11];
  const float* c2b1 = (const float*)d_in[12];
  const float* c2w2 = (const float*)d_in[13];
  const float* c2b2 = (const float*)d_in[14];
  const float* mw1 = (const float*)d_in[15];
  const float* mb1 = (const float*)d_in[16];
  const float* mw2 = (const float*)d_in[17];
  const float* mb2 = (const float*)d_in[18];
  const float* mw3 = (const float*)d_in[19];
  const float* mb3 = (const float*)d_in[20];
  float* out = (float*)d_out;

  char* ws = (char*)d_ws;
  size_t off = 0;
  auto alloc = [&](size_t bytes) {
    void* p = ws + off;
    off += (bytes + 255) & ~(size_t)255;
    return p;
  };
  _Float16* x16a = (_Float16*)alloc((size_t)N_NODES * D * 2);
  _Float16* x16b = (_Float16*)alloc((size_t)N_NODES * D * 2);
  _Float16* h16 = (_Float16*)alloc((size_t)N_NODES * D * 2);
  _Float16* x2_16 = (_Float16*)alloc((size_t)N_NODES * D * 2);
  int* deg = (int*)alloc((size_t)N_NODES * 4);
  int* row_ptr = (int*)alloc((size_t)(N_NODES + 1) * 4);
  int* bsum = (int*)alloc(64 * 4);
  int* csr1 = (int*)alloc((size_t)N_EDGES * 4);
  unsigned short* dst16 = (unsigned short*)alloc((size_t)N_EDGES * 2);
  int* epack = (int*)alloc((size_t)N_EDGES * 4);
  _Float16* hcat16 = (_Float16*)alloc((size_t)N_GRAPH * 352 * 2);
  _Float16* cWf = (_Float16*)alloc((size_t)4 * 2048 * 8 * 2);
  _Float16* W1f = (_Float16*)alloc((size_t)352 * 64 * 8 * 2);
  _Float16* W2f = (_Float16*)alloc((size_t)256 * 64 * 8 * 2);
  int* cnt = (int*)alloc(2 * 4);

  k_prep<<<256, 256, 0, stream>>>(c1w1, c1w2, c2w1, c2w2, mw1, mw2,
                                  cWf, W1f, W2f, deg, cnt);
  k_atom_count<<<6250 + 2500, 256, 0, stream>>>(x_feat, atom_emb, x16a,
                                                ei, bondf, deg, dst16, epack);

  int nb = (N_NODES + 1023) / 1024;
  k_scan_blocks<<<nb, 1024, 0, stream>>>(deg, row_ptr, bsum);
  k_scan_add<<<nb, 1024, 0, stream>>>(row_ptr, bsum);
  k_fill_range<<<256, 256, 0, stream>>>(dst16, epack, row_ptr, csr1);

  int ctiles = (N_NODES + 127) / 128;  // 391
  // conv1
  k_agg<<<2048, 256, 0, stream>>>(x16a, row_ptr, csr1, bond_emb, h16, cnt + 0);
  k_conv<<<ctiles, 256, 0, stream>>>(h16, cWf + 0 * 16384, c1b1,
                                     cWf + 1 * 16384, c1b2, x16b);
  // conv2
  k_agg<<<2048, 256, 0, stream>>>(x16b, row_ptr, csr1, bond_emb, h16, cnt + 1);
  k_conv<<<ctiles, 256, 0, stream>>>(h16, cWf + 2 * 16384, c2b1,
                                     cWf + 3 * 16384, c2b2, x2_16);

  // pool + fused head MLP
  k_pool<<<N_GRAPH / 4, 256, 0, stream>>>(x2_16, batch, rdkit, hcat16);
  k_mlp_head<<<64, 256, 0, stream>>>(hcat16, W1f, mb1, W2f, mb2, mw3, mb3, out);

  (void)in_sizes; (void)n_in; (void)out_size; (void)ws_size;
}

// Round 10
// 830.500 us; speedup vs baseline: 1.6345x; 1.6345x over previous
//
#include <hip/hip_runtime.h>

#define N_NODES 50000
#define N_EDGES 640000
#define N_GRAPH 1024
#define D 128
#define RD 200

typedef __attribute__((ext_vector_type(4))) float f32x4;
typedef __attribute__((ext_vector_type(8))) float f32x8;
typedef __attribute__((ext_vector_type(2))) _Float16 half2v;
typedef __attribute__((ext_vector_type(4))) _Float16 half4;
typedef __attribute__((ext_vector_type(8))) _Float16 half8;

static __device__ __forceinline__ int lbound(const int* a, int n, int v) {
  int lo = 0, hi = n;
  while (lo < hi) { int m = (lo + hi) >> 1; if (a[m] < v) lo = m + 1; else hi = m; }
  return lo;
}

// ---- prep: weights -> fp16 fragment order; zero deg + steal counters ----
__global__ void k_prep(const float* __restrict__ w0, const float* __restrict__ w1,
                       const float* __restrict__ w2, const float* __restrict__ w3,
                       const float* __restrict__ mw1, const float* __restrict__ mw2,
                       _Float16* __restrict__ cWf,   // [4][32*64*8]
                       _Float16* __restrict__ W1f,   // [352*64*8]
                       _Float16* __restrict__ W2f,   // [256*64*8]
                       int* __restrict__ deg, int* __restrict__ cnt) {
  int t = blockIdx.x * 256 + threadIdx.x;  // 0..65535
  if (t < N_NODES) deg[t] = 0;
  if (t == 0) { cnt[0] = 0; cnt[1] = 0; }
  if (t < 8192) {
    int mat = t >> 11, r = t & 2047;
    int frag = r >> 6, lane = r & 63;
    int n0 = frag >> 2, kk = frag & 3;
    int n = n0 * 16 + (lane & 15);
    int kb = (lane >> 4) * 8 + kk * 32;
    const float* W = (mat == 0) ? w0 : (mat == 1) ? w1 : (mat == 2) ? w2 : w3;
    half8 o;
#pragma unroll
    for (int j = 0; j < 8; ++j) o[j] = (_Float16)W[(kb + j) * D + n];
    *(half8*)&cWf[((size_t)mat * 2048 + r) * 8] = o;
  } else if (t < 8192 + 22528) {
    int u = t - 8192;
    int frag = u >> 6, lane = u & 63;
    int n0 = frag / 11, kk = frag % 11;
    int n = n0 * 16 + (lane & 15);
    int kb = (lane >> 4) * 8 + kk * 32;
    half8 o;
#pragma unroll
    for (int j = 0; j < 8; ++j) {
      int k = kb + j;
      o[j] = (k < 328) ? (_Float16)mw1[k * 512 + n] : (_Float16)0.f;
    }
    *(half8*)&W1f[(size_t)u * 8] = o;
  } else if (t < 8192 + 22528 + 16384) {
    int u = t - 8192 - 22528;
    int frag = u >> 6, lane = u & 63;
    int n0 = frag >> 4, kk = frag & 15;
    int n = n0 * 16 + (lane & 15);
    int kb = (lane >> 4) * 8 + kk * 32;
    half8 o;
#pragma unroll
    for (int j = 0; j < 8; ++j) o[j] = (_Float16)mw2[(kb + j) * 256 + n];
    *(half8*)&W2f[(size_t)u * 8] = o;
  }
}

// fused: atom encoder (fp16) + degree count + dst16 + edge pack
__global__ void k_atom_count(const int* __restrict__ xf, const float* __restrict__ emb,
                             _Float16* __restrict__ x16,
                             const int* __restrict__ ei, const int* __restrict__ bondf,
                             int* __restrict__ deg,
                             unsigned short* __restrict__ dst16,
                             int* __restrict__ epack) {
  if (blockIdx.x < 6250) {
    int t = blockIdx.x * 256 + threadIdx.x;  // exactly 50000*32
    int node = t >> 5, c = (t & 31) << 2;
    float a0 = 0.f, a1 = 0.f, a2 = 0.f, a3 = 0.f;
#pragma unroll
    for (int f = 0; f < 9; ++f) {
      int v = xf[node * 9 + f];
      float4 e4 = *(const float4*)&emb[(f * 64 + v) * D + c];
      a0 += e4.x; a1 += e4.y; a2 += e4.z; a3 += e4.w;
    }
    half4 o;
    o.x = (_Float16)a0; o.y = (_Float16)a1; o.z = (_Float16)a2; o.w = (_Float16)a3;
    *(half4*)&x16[(size_t)node * D + c] = o;
  } else {
    int e = (blockIdx.x - 6250) * 256 + threadIdx.x;
    if (e < N_EDGES) {
      int d = ei[N_EDGES + e];
      atomicAdd(&deg[d], 1);
      dst16[e] = (unsigned short)d;
      int s = ei[e];
      int f0 = bondf[e * 3], f1 = bondf[e * 3 + 1], f2 = bondf[e * 3 + 2];
      epack[e] = s | (f0 << 16) | (f1 << 20) | (f2 << 24);
    }
  }
}

__global__ void k_scan_blocks(const int* __restrict__ deg, int* __restrict__ excl,
                              int* __restrict__ bsum) {
  __shared__ int sd[1024];
  int i = blockIdx.x * 1024 + threadIdx.x;
  int v = (i < N_NODES) ? deg[i] : 0;
  sd[threadIdx.x] = v;
  __syncthreads();
  for (int off = 1; off < 1024; off <<= 1) {
    int t = (threadIdx.x >= (unsigned)off) ? sd[threadIdx.x - off] : 0;
    __syncthreads();
    sd[threadIdx.x] += t;
    __syncthreads();
  }
  if (i < N_NODES) excl[i] = sd[threadIdx.x] - v;
  if (threadIdx.x == 1023) bsum[blockIdx.x] = sd[1023];
}

// add block-prefix; also materialize cursor copy; row_ptr[N] = E
__global__ void k_scan_add(int* __restrict__ row_ptr, int* __restrict__ cursor,
                           const int* __restrict__ bsum) {
  int off = 0;
  for (int b = 0; b < blockIdx.x; ++b) off += bsum[b];
  int i = blockIdx.x * 1024 + threadIdx.x;
  if (i < N_NODES) {
    int r = row_ptr[i] + off;
    row_ptr[i] = r;
    cursor[i] = r;
  }
  if (blockIdx.x == 0 && threadIdx.x == 0) row_ptr[N_NODES] = N_EDGES;
}

// scatter fill: coalesced dst16/epack streams, atomic cursor, 4B csr writes
__global__ void k_fill(const unsigned short* __restrict__ dst16,
                       const int* __restrict__ epack,
                       int* __restrict__ cursor, int* __restrict__ csr1) {
  int e = blockIdx.x * 256 + threadIdx.x;
  if (e >= N_EDGES) return;
  int d = dst16[e];
  int pos = atomicAdd(&cursor[d], 1);
  csr1[pos] = epack[e];
}

// out[i] = x[i] + sum_j relu(x[src] + bond_emb_sum)
// packed csr (src|f<<16), fp16 packed math, wave work-stealing (chunk 4).
__global__ __launch_bounds__(256) void k_agg(
    const _Float16* __restrict__ x16, const int* __restrict__ row_ptr,
    const int* __restrict__ csr1, const float* __restrict__ bemb,
    _Float16* __restrict__ out, int* __restrict__ cnt) {
  __shared__ half8 sB[48 * 16];  // 12 KB fp16 bond table
  for (int t = threadIdx.x; t < 768; t += blockDim.x) {
    float4 v0 = *(const float4*)&bemb[t * 8];
    float4 v1 = *(const float4*)&bemb[t * 8 + 4];
    half8 h;
    h[0] = (_Float16)v0.x; h[1] = (_Float16)v0.y; h[2] = (_Float16)v0.z; h[3] = (_Float16)v0.w;
    h[4] = (_Float16)v1.x; h[5] = (_Float16)v1.y; h[6] = (_Float16)v1.z; h[7] = (_Float16)v1.w;
    sB[t] = h;
  }
  __syncthreads();
  int lane = threadIdx.x & 63;
  int quad = lane >> 4;
  int l15 = lane & 15;
  int c8 = l15 * 8;
  for (;;) {
    int base;
    if (lane == 0) base = atomicAdd(cnt, 4);
    base = __shfl(base, 0);
    if (base >= N_NODES) break;
    int iend = base + 4; if (iend > N_NODES) iend = N_NODES;
    for (int i = base; i < iend; ++i) {
      f32x8 ac[2];
      ac[0] = (f32x8)(0.f); ac[1] = (f32x8)(0.f);
      int e0 = row_ptr[i], e1 = row_ptr[i + 1];
      int j = e0 + quad;
#define EDGE(u, jj)                                                          \
      {                                                                      \
        unsigned ed = (unsigned)csr1[jj];                                    \
        half8 xr = *(const half8*)&x16[(size_t)(ed & 0xFFFF) * D + c8];      \
        unsigned p = ed >> 16;                                               \
        half8 m16 = (xr + sB[(p & 15) * 16 + l15]) +                         \
                    (sB[256 + ((p >> 4) & 15) * 16 + l15] +                  \
                     sB[512 + (p >> 8) * 16 + l15]);                         \
        f32x8 m = __builtin_convertvector(m16, f32x8);                       \
        _Pragma("unroll")                                                    \
        for (int tt = 0; tt < 8; ++tt) ac[u][tt] += fmaxf(m[tt], 0.f);       \
      }
      for (; j + 4 < e1; j += 8) { EDGE(0, j) EDGE(1, j + 4) }
      for (; j < e1; j += 4) EDGE(0, j)
#undef EDGE
      f32x8 acc = ac[0] + ac[1];
#pragma unroll
      for (int tt = 0; tt < 8; ++tt) {
        acc[tt] += __shfl_xor(acc[tt], 16);
        acc[tt] += __shfl_xor(acc[tt], 32);
      }
      if (quad == 0) {
        half8 sr = *(const half8*)&x16[(size_t)i * D + c8];
        f32x8 o = __builtin_convertvector(sr, f32x8) + acc;
        *(half8*)&out[(size_t)i * D + c8] = __builtin_convertvector(o, half8);
      }
    }
  }
}

// fused GINE nn: out = relu(A@W1+b1)@W2+b2 ; fp16 MFMA, W staged in LDS.
__global__ __launch_bounds__(256) void k_conv(
    const _Float16* __restrict__ A,
    const _Float16* __restrict__ W1f, const float* __restrict__ b1,
    const _Float16* __restrict__ W2f, const float* __restrict__ b2,
    _Float16* __restrict__ O16) {
  __shared__ _Float16 sW[2048 * 8];
  __shared__ _Float16 sI[128 * 136];
  int tid = threadIdx.x, w = tid >> 6, lane = tid & 63;
  int m0 = blockIdx.x * 128;
  int col16 = lane & 15, q = lane >> 4;
  for (int t = tid; t < 2048; t += 256)
    *(float4*)&sW[t * 8] = *(const float4*)&W1f[(size_t)t * 8];
  half8 afr[2][4];
#pragma unroll
  for (int f = 0; f < 2; ++f) {
    int row = m0 + w * 32 + f * 16 + col16;
    if (row >= N_NODES) row = N_NODES - 1;
    const _Float16* Ar = A + (size_t)row * D + q * 8;
#pragma unroll
    for (int kk = 0; kk < 4; ++kk) afr[f][kk] = *(const half8*)(Ar + kk * 32);
  }
  __syncthreads();
#pragma unroll
  for (int n0 = 0; n0 < 8; ++n0) {
    f32x4 a0 = {0.f, 0.f, 0.f, 0.f}, a1 = {0.f, 0.f, 0.f, 0.f};
#pragma unroll
    for (int kk = 0; kk < 4; ++kk) {
      half8 b = *(const half8*)&sW[((n0 * 4 + kk) * 64 + lane) * 8];
      a0 = __builtin_amdgcn_mfma_f32_16x16x32_f16(afr[0][kk], b, a0, 0, 0, 0);
      a1 = __builtin_amdgcn_mfma_f32_16x16x32_f16(afr[1][kk], b, a1, 0, 0, 0);
    }
    float bb = b1[n0 * 16 + col16];
#pragma unroll
    for (int r = 0; r < 4; ++r) {
      sI[(w * 32 + q * 4 + r) * 136 + n0 * 16 + col16] = (_Float16)fmaxf(a0[r] + bb, 0.f);
      sI[(w * 32 + 16 + q * 4 + r) * 136 + n0 * 16 + col16] = (_Float16)fmaxf(a1[r] + bb, 0.f);
    }
  }
  __syncthreads();
  for (int t = tid; t < 2048; t += 256)
    *(float4*)&sW[t * 8] = *(const float4*)&W2f[(size_t)t * 8];
  half8 a2[2][4];
#pragma unroll
  for (int f = 0; f < 2; ++f) {
    const _Float16* tr = &sI[(w * 32 + f * 16 + col16) * 136 + q * 8];
#pragma unroll
    for (int kk = 0; kk < 4; ++kk) a2[f][kk] = *(const half8*)(tr + kk * 32);
  }
  __syncthreads();
#pragma unroll
  for (int n0 = 0; n0 < 8; ++n0) {
    f32x4 a0 = {0.f, 0.f, 0.f, 0.f}, a1 = {0.f, 0.f, 0.f, 0.f};
#pragma unroll
    for (int kk = 0; kk < 4; ++kk) {
      half8 b = *(const half8*)&sW[((n0 * 4 + kk) * 64 + lane) * 8];
      a0 = __builtin_amdgcn_mfma_f32_16x16x32_f16(a2[0][kk], b, a0, 0, 0, 0);
      a1 = __builtin_amdgcn_mfma_f32_16x16x32_f16(a2[1][kk], b, a1, 0, 0, 0);
    }
    int col = n0 * 16 + col16;
    float bb = b2[col];
#pragma unroll
    for (int r = 0; r < 4; ++r) {
      int r0 = m0 + w * 32 + q * 4 + r;
      int r1 = r0 + 16;
      if (r0 < N_NODES) O16[(size_t)r0 * D + col] = (_Float16)(a0[r] + bb);
      if (r1 < N_NODES) O16[(size_t)r1 * D + col] = (_Float16)(a1[r] + bb);
    }
  }
}

// fused head: pool 16 graphs into LDS, then 3-layer MLP (MFMA fp16)
__global__ __launch_bounds__(256) void k_head(
    const _Float16* __restrict__ x, const int* __restrict__ batch,
    const float* __restrict__ rdkit,
    const _Float16* __restrict__ W1f, const float* __restrict__ B1,
    const _Float16* __restrict__ W2f, const float* __restrict__ B2,
    const float* __restrict__ W3, const float* __restrict__ B3,
    float* __restrict__ out) {
  __shared__ _Float16 sHC[16 * 352];  // pooled+rdkit, fp16
  __shared__ _Float16 sH[16 * 520];   // h1
  __shared__ float sRed[4][16];
  int w = threadIdx.x >> 6, lane = threadIdx.x & 63;
  int m0 = blockIdx.x * 16;
  int col16 = lane & 15, q = lane >> 4;
  // pool: wave w handles graphs m0+w*4 .. +3
#pragma unroll
  for (int gg = 0; gg < 4; ++gg) {
    int gl = w * 4 + gg;
    int g = m0 + gl;
    int lo = lbound(batch, N_NODES, g);
    int hi = lbound(batch, N_NODES, g + 1);
    float a0 = 0.f, a1 = 0.f;
    for (int i = lo; i < hi; ++i) {
      half2v v = *(const half2v*)&x[(size_t)i * D + lane * 2];
      a0 += (float)v.x; a1 += (float)v.y;
    }
    float inv = 1.f / fmaxf((float)(hi - lo), 1.f);
    sHC[gl * 352 + lane * 2] = (_Float16)(a0 * inv);
    sHC[gl * 352 + lane * 2 + 1] = (_Float16)(a1 * inv);
    for (int r = lane; r < RD; r += 64)
      sHC[gl * 352 + D + r] = (_Float16)rdkit[(size_t)g * RD + r];
    if (lane < 24) sHC[gl * 352 + 328 + lane] = (_Float16)0.f;
  }
  __syncthreads();
  // layer 1: h1 = relu(hcat@W1+b1) -> sH
  {
    const _Float16* Ar = &sHC[col16 * 352 + q * 8];
    half8 afr[11];
#pragma unroll
    for (int kk = 0; kk < 11; ++kk) afr[kk] = *(const half8*)(Ar + kk * 32);
#pragma unroll
    for (int u = 0; u < 8; ++u) {
      int n0 = w * 8 + u;
      f32x4 acc = {0.f, 0.f, 0.f, 0.f};
#pragma unroll
      for (int kk = 0; kk < 11; ++kk) {
        half8 b = *(const half8*)&W1f[(size_t)((n0 * 11 + kk) * 64 + lane) * 8];
        acc = __builtin_amdgcn_mfma_f32_16x16x32_f16(afr[kk], b, acc, 0, 0, 0);
      }
      float bb = B1[n0 * 16 + col16];
#pragma unroll
      for (int r = 0; r < 4; ++r)
        sH[(q * 4 + r) * 520 + n0 * 16 + col16] = (_Float16)fmaxf(acc[r] + bb, 0.f);
    }
  }
  __syncthreads();
  // layers 2+3
  half8 a2[16];
  {
    const _Float16* tr = &sH[col16 * 520 + q * 8];
#pragma unroll
    for (int kk = 0; kk < 16; ++kk) a2[kk] = *(const half8*)(tr + kk * 32);
  }
  f32x4 acc[4];
#pragma unroll
  for (int u = 0; u < 4; ++u) acc[u] = (f32x4){0.f, 0.f, 0.f, 0.f};
#pragma unroll
  for (int kk = 0; kk < 16; ++kk) {
#pragma unroll
    for (int u = 0; u < 4; ++u) {
      int n0 = w * 4 + u;
      half8 b = *(const half8*)&W2f[(size_t)((n0 * 16 + kk) * 64 + lane) * 8];
      acc[u] = __builtin_amdgcn_mfma_f32_16x16x32_f16(a2[kk], b, acc[u], 0, 0, 0);
    }
  }
  float p[4] = {0.f, 0.f, 0.f, 0.f};
#pragma unroll
  for (int u = 0; u < 4; ++u) {
    int col = (w * 4 + u) * 16 + col16;
    float bb = B2[col], w3 = W3[col];
#pragma unroll
    for (int r = 0; r < 4; ++r) p[r] += fmaxf(acc[u][r] + bb, 0.f) * w3;
  }
#pragma unroll
  for (int r = 0; r < 4; ++r) {
    p[r] += __shfl_xor(p[r], 1);
    p[r] += __shfl_xor(p[r], 2);
    p[r] += __shfl_xor(p[r], 4);
    p[r] += __shfl_xor(p[r], 8);
  }
  if (col16 == 0) {
#pragma unroll
    for (int r = 0; r < 4; ++r) sRed[w][q * 4 + r] = p[r];
  }
  __syncthreads();
  if (threadIdx.x < 16) {
    float s = sRed[0][threadIdx.x] + sRed[1][threadIdx.x] +
              sRed[2][threadIdx.x] + sRed[3][threadIdx.x];
    out[m0 + threadIdx.x] = s + B3[0];
  }
}

extern "C" void kernel_launch(void* const* d_in, const int* in_sizes, int n_in,
                              void* d_out, int out_size, void* d_ws, size_t ws_size,
                              hipStream_t stream) {
  const int* x_feat = (const int*)d_in[0];
  const int* ei = (const int*)d_in[1];
  const int* bondf = (const int*)d_in[2];
  const int* batch = (const int*)d_in[3];
  const float* rdkit = (const float*)d_in[4];
  const float* atom_emb = (const float*)d_in[5];
  const float* bond_emb = (const float*)d_in[6];
  const float* c1w1 = (const float*)d_in[7];
  const float* c1b1 = (const float*)d_in[8];
  const float* c1w2 = (const float*)d_in[9];
  const float* c1b2 = (const float*)d_in[10];
  const float* c2w1 = (const float*)d_in[11];
  const float* c2b1 = (const float*)d_in[12];
  const float* c2w2 = (const float*)d_in[13];
  const float* c2b2 = (const float*)d_in[14];
  const float* mw1 = (const float*)d_in[15];
  const float* mb1 = (const float*)d_in[16];
  const float* mw2 = (const float*)d_in[17];
  const float* mb2 = (const float*)d_in[18];
  const float* mw3 = (const float*)d_in[19];
  const float* mb3 = (const float*)d_in[20];
  float* out = (float*)d_out;

  char* ws = (char*)d_ws;
  size_t off = 0;
  auto alloc = [&](size_t bytes) {
    void* p = ws + off;
    off += (bytes + 255) & ~(size_t)255;
    return p;
  };
  _Float16* x16a = (_Float16*)alloc((size_t)N_NODES * D * 2);
  _Float16* x16b = (_Float16*)alloc((size_t)N_NODES * D * 2);
  _Float16* h16 = (_Float16*)alloc((size_t)N_NODES * D * 2);
  _Float16* x2_16 = (_Float16*)alloc((size_t)N_NODES * D * 2);
  int* deg = (int*)alloc((size_t)N_NODES * 4);
  int* cursor = (int*)alloc((size_t)N_NODES * 4);
  int* row_ptr = (int*)alloc((size_t)(N_NODES + 1) * 4);
  int* bsum = (int*)alloc(64 * 4);
  int* csr1 = (int*)alloc((size_t)N_EDGES * 4);
  unsigned short* dst16 = (unsigned short*)alloc((size_t)N_EDGES * 2);
  int* epack = (int*)alloc((size_t)N_EDGES * 4);
  _Float16* cWf = (_Float16*)alloc((size_t)4 * 2048 * 8 * 2);
  _Float16* W1f = (_Float16*)alloc((size_t)352 * 64 * 8 * 2);
  _Float16* W2f = (_Float16*)alloc((size_t)256 * 64 * 8 * 2);
  int* cnt = (int*)alloc(2 * 4);

  k_prep<<<256, 256, 0, stream>>>(c1w1, c1w2, c2w1, c2w2, mw1, mw2,
                                  cWf, W1f, W2f, deg, cnt);
  k_atom_count<<<6250 + 2500, 256, 0, stream>>>(x_feat, atom_emb, x16a,
                                                ei, bondf, deg, dst16, epack);

  int nb = (N_NODES + 1023) / 1024;
  k_scan_blocks<<<nb, 1024, 0, stream>>>(deg, row_ptr, bsum);
  k_scan_add<<<nb, 1024, 0, stream>>>(row_ptr, cursor, bsum);
  k_fill<<<(N_EDGES + 255) / 256, 256, 0, stream>>>(dst16, epack, cursor, csr1);

  int ctiles = (N_NODES + 127) / 128;  // 391
  // conv1
  k_agg<<<2048, 256, 0, stream>>>(x16a, row_ptr, csr1, bond_emb, h16, cnt + 0);
  k_conv<<<ctiles, 256, 0, stream>>>(h16, cWf + 0 * 16384, c1b1,
                                     cWf + 1 * 16384, c1b2, x16b);
  // conv2
  k_agg<<<2048, 256, 0, stream>>>(x16b, row_ptr, csr1, bond_emb, h16, cnt + 1);
  k_conv<<<ctiles, 256, 0, stream>>>(h16, cWf + 2 * 16384, c2b1,
                                     cWf + 3 * 16384, c2b2, x2_16);

  // fused pool + head MLP
  k_head<<<64, 256, 0, stream>>>(x2_16, batch, rdkit, W1f, mb1, W2f, mb2,
                                 mw3, mb3, out);

  (void)in_sizes; (void)n_in; (void)out_size; (void)ws_size;
}

// Round 11
// 407.617 us; speedup vs baseline: 3.3303x; 2.0375x over previous
//
#include <hip/hip_runtime.h>

#define N_NODES 50000
#define N_EDGES 640000
#define N_GRAPH 1024
#define D 128
#define RD 200

typedef __attribute__((ext_vector_type(4))) float f32x4;
typedef __attribute__((ext_vector_type(8))) float f32x8;
typedef __attribute__((ext_vector_type(2))) _Float16 half2v;
typedef __attribute__((ext_vector_type(4))) _Float16 half4;
typedef __attribute__((ext_vector_type(8))) _Float16 half8;

static __device__ __forceinline__ int lbound(const int* a, int n, int v) {
  int lo = 0, hi = n;
  while (lo < hi) { int m = (lo + hi) >> 1; if (a[m] < v) lo = m + 1; else hi = m; }
  return lo;
}

// ---- prep: weights -> fp16 fragment order; zero deg ----
__global__ void k_prep(const float* __restrict__ w0, const float* __restrict__ w1,
                       const float* __restrict__ w2, const float* __restrict__ w3,
                       const float* __restrict__ mw1, const float* __restrict__ mw2,
                       _Float16* __restrict__ cWf,   // [4][32*64*8]
                       _Float16* __restrict__ W1f,   // [352*64*8]
                       _Float16* __restrict__ W2f,   // [256*64*8]
                       int* __restrict__ deg) {
  int t = blockIdx.x * 256 + threadIdx.x;  // 0..65535
  if (t < N_NODES) deg[t] = 0;
  if (t < 8192) {
    int mat = t >> 11, r = t & 2047;
    int frag = r >> 6, lane = r & 63;
    int n0 = frag >> 2, kk = frag & 3;
    int n = n0 * 16 + (lane & 15);
    int kb = (lane >> 4) * 8 + kk * 32;
    const float* W = (mat == 0) ? w0 : (mat == 1) ? w1 : (mat == 2) ? w2 : w3;
    half8 o;
#pragma unroll
    for (int j = 0; j < 8; ++j) o[j] = (_Float16)W[(kb + j) * D + n];
    *(half8*)&cWf[((size_t)mat * 2048 + r) * 8] = o;
  } else if (t < 8192 + 22528) {
    int u = t - 8192;
    int frag = u >> 6, lane = u & 63;
    int n0 = frag / 11, kk = frag % 11;
    int n = n0 * 16 + (lane & 15);
    int kb = (lane >> 4) * 8 + kk * 32;
    half8 o;
#pragma unroll
    for (int j = 0; j < 8; ++j) {
      int k = kb + j;
      o[j] = (k < 328) ? (_Float16)mw1[k * 512 + n] : (_Float16)0.f;
    }
    *(half8*)&W1f[(size_t)u * 8] = o;
  } else if (t < 8192 + 22528 + 16384) {
    int u = t - 8192 - 22528;
    int frag = u >> 6, lane = u & 63;
    int n0 = frag >> 4, kk = frag & 15;
    int n = n0 * 16 + (lane & 15);
    int kb = (lane >> 4) * 8 + kk * 32;
    half8 o;
#pragma unroll
    for (int j = 0; j < 8; ++j) o[j] = (_Float16)mw2[(kb + j) * 256 + n];
    *(half8*)&W2f[(size_t)u * 8] = o;
  }
}

// fused: atom encoder (fp16) + degree count + dst16 + edge pack
__global__ void k_atom_count(const int* __restrict__ xf, const float* __restrict__ emb,
                             _Float16* __restrict__ x16,
                             const int* __restrict__ ei, const int* __restrict__ bondf,
                             int* __restrict__ deg,
                             unsigned short* __restrict__ dst16,
                             int* __restrict__ epack) {
  if (blockIdx.x < 6250) {
    int t = blockIdx.x * 256 + threadIdx.x;  // exactly 50000*32
    int node = t >> 5, c = (t & 31) << 2;
    float a0 = 0.f, a1 = 0.f, a2 = 0.f, a3 = 0.f;
#pragma unroll
    for (int f = 0; f < 9; ++f) {
      int v = xf[node * 9 + f];
      float4 e4 = *(const float4*)&emb[(f * 64 + v) * D + c];
      a0 += e4.x; a1 += e4.y; a2 += e4.z; a3 += e4.w;
    }
    half4 o;
    o.x = (_Float16)a0; o.y = (_Float16)a1; o.z = (_Float16)a2; o.w = (_Float16)a3;
    *(half4*)&x16[(size_t)node * D + c] = o;
  } else {
    int e = (blockIdx.x - 6250) * 256 + threadIdx.x;
    if (e < N_EDGES) {
      int d = ei[N_EDGES + e];
      atomicAdd(&deg[d], 1);
      dst16[e] = (unsigned short)d;
      int s = ei[e];
      int f0 = bondf[e * 3], f1 = bondf[e * 3 + 1], f2 = bondf[e * 3 + 2];
      epack[e] = s | (f0 << 16) | (f1 << 20) | (f2 << 24);
    }
  }
}

__global__ void k_scan_blocks(const int* __restrict__ deg, int* __restrict__ excl,
                              int* __restrict__ bsum) {
  __shared__ int sd[1024];
  int i = blockIdx.x * 1024 + threadIdx.x;
  int v = (i < N_NODES) ? deg[i] : 0;
  sd[threadIdx.x] = v;
  __syncthreads();
  for (int off = 1; off < 1024; off <<= 1) {
    int t = (threadIdx.x >= (unsigned)off) ? sd[threadIdx.x - off] : 0;
    __syncthreads();
    sd[threadIdx.x] += t;
    __syncthreads();
  }
  if (i < N_NODES) excl[i] = sd[threadIdx.x] - v;
  if (threadIdx.x == 1023) bsum[blockIdx.x] = sd[1023];
}

// add block-prefix; materialize cursor copy; row_ptr[N] = E
__global__ void k_scan_add(int* __restrict__ row_ptr, int* __restrict__ cursor,
                           const int* __restrict__ bsum) {
  int off = 0;
  for (int b = 0; b < blockIdx.x; ++b) off += bsum[b];
  int i = blockIdx.x * 1024 + threadIdx.x;
  if (i < N_NODES) {
    int r = row_ptr[i] + off;
    row_ptr[i] = r;
    cursor[i] = r;
  }
  if (blockIdx.x == 0 && threadIdx.x == 0) row_ptr[N_NODES] = N_EDGES;
}

// scatter fill: coalesced dst16/epack streams, atomic cursor, 4B csr writes
__global__ void k_fill(const unsigned short* __restrict__ dst16,
                       const int* __restrict__ epack,
                       int* __restrict__ cursor, int* __restrict__ csr1) {
  int e = blockIdx.x * 256 + threadIdx.x;
  if (e >= N_EDGES) return;
  int d = dst16[e];
  int pos = atomicAdd(&cursor[d], 1);
  csr1[pos] = epack[e];
}

// out[i] = x[i] + sum_j relu(x[src] + bond_emb_sum)
// packed csr (src|f<<16), fp16 packed math, static strided node assignment.
__global__ __launch_bounds__(256) void k_agg(
    const _Float16* __restrict__ x16, const int* __restrict__ row_ptr,
    const int* __restrict__ csr1, const float* __restrict__ bemb,
    _Float16* __restrict__ out) {
  __shared__ half8 sB[48 * 16];  // 12 KB fp16 bond table
  for (int t = threadIdx.x; t < 768; t += blockDim.x) {
    float4 v0 = *(const float4*)&bemb[t * 8];
    float4 v1 = *(const float4*)&bemb[t * 8 + 4];
    half8 h;
    h[0] = (_Float16)v0.x; h[1] = (_Float16)v0.y; h[2] = (_Float16)v0.z; h[3] = (_Float16)v0.w;
    h[4] = (_Float16)v1.x; h[5] = (_Float16)v1.y; h[6] = (_Float16)v1.z; h[7] = (_Float16)v1.w;
    sB[t] = h;
  }
  __syncthreads();
  int lane = threadIdx.x & 63;
  int quad = lane >> 4;
  int l15 = lane & 15;
  int c8 = l15 * 8;
  int wid = blockIdx.x * (blockDim.x >> 6) + (threadIdx.x >> 6);
  int nw = gridDim.x * (blockDim.x >> 6);
  for (int i = wid; i < N_NODES; i += nw) {
    f32x8 ac[2];
    ac[0] = (f32x8)(0.f); ac[1] = (f32x8)(0.f);
    int e0 = row_ptr[i], e1 = row_ptr[i + 1];
    int j = e0 + quad;
#define EDGE(u, jj)                                                          \
    {                                                                        \
      unsigned ed = (unsigned)csr1[jj];                                      \
      half8 xr = *(const half8*)&x16[(size_t)(ed & 0xFFFF) * D + c8];        \
      unsigned p = ed >> 16;                                                 \
      half8 m16 = (xr + sB[(p & 15) * 16 + l15]) +                           \
                  (sB[256 + ((p >> 4) & 15) * 16 + l15] +                    \
                   sB[512 + (p >> 8) * 16 + l15]);                           \
      f32x8 m = __builtin_convertvector(m16, f32x8);                         \
      _Pragma("unroll")                                                      \
      for (int tt = 0; tt < 8; ++tt) ac[u][tt] += fmaxf(m[tt], 0.f);         \
    }
    for (; j + 4 < e1; j += 8) { EDGE(0, j) EDGE(1, j + 4) }
    for (; j < e1; j += 4) EDGE(0, j)
#undef EDGE
    f32x8 acc = ac[0] + ac[1];
#pragma unroll
    for (int tt = 0; tt < 8; ++tt) {
      acc[tt] += __shfl_xor(acc[tt], 16);
      acc[tt] += __shfl_xor(acc[tt], 32);
    }
    if (quad == 0) {
      half8 sr = *(const half8*)&x16[(size_t)i * D + c8];
      f32x8 o = __builtin_convertvector(sr, f32x8) + acc;
      *(half8*)&out[(size_t)i * D + c8] = __builtin_convertvector(o, half8);
    }
  }
}

// fused GINE nn: out = relu(A@W1+b1)@W2+b2 ; fp16 MFMA, W staged in LDS.
__global__ __launch_bounds__(256) void k_conv(
    const _Float16* __restrict__ A,
    const _Float16* __restrict__ W1f, const float* __restrict__ b1,
    const _Float16* __restrict__ W2f, const float* __restrict__ b2,
    _Float16* __restrict__ O16) {
  __shared__ _Float16 sW[2048 * 8];
  __shared__ _Float16 sI[128 * 136];
  int tid = threadIdx.x, w = tid >> 6, lane = tid & 63;
  int m0 = blockIdx.x * 128;
  int col16 = lane & 15, q = lane >> 4;
  for (int t = tid; t < 2048; t += 256)
    *(float4*)&sW[t * 8] = *(const float4*)&W1f[(size_t)t * 8];
  half8 afr[2][4];
#pragma unroll
  for (int f = 0; f < 2; ++f) {
    int row = m0 + w * 32 + f * 16 + col16;
    if (row >= N_NODES) row = N_NODES - 1;
    const _Float16* Ar = A + (size_t)row * D + q * 8;
#pragma unroll
    for (int kk = 0; kk < 4; ++kk) afr[f][kk] = *(const half8*)(Ar + kk * 32);
  }
  __syncthreads();
#pragma unroll
  for (int n0 = 0; n0 < 8; ++n0) {
    f32x4 a0 = {0.f, 0.f, 0.f, 0.f}, a1 = {0.f, 0.f, 0.f, 0.f};
#pragma unroll
    for (int kk = 0; kk < 4; ++kk) {
      half8 b = *(const half8*)&sW[((n0 * 4 + kk) * 64 + lane) * 8];
      a0 = __builtin_amdgcn_mfma_f32_16x16x32_f16(afr[0][kk], b, a0, 0, 0, 0);
      a1 = __builtin_amdgcn_mfma_f32_16x16x32_f16(afr[1][kk], b, a1, 0, 0, 0);
    }
    float bb = b1[n0 * 16 + col16];
#pragma unroll
    for (int r = 0; r < 4; ++r) {
      sI[(w * 32 + q * 4 + r) * 136 + n0 * 16 + col16] = (_Float16)fmaxf(a0[r] + bb, 0.f);
      sI[(w * 32 + 16 + q * 4 + r) * 136 + n0 * 16 + col16] = (_Float16)fmaxf(a1[r] + bb, 0.f);
    }
  }
  __syncthreads();
  for (int t = tid; t < 2048; t += 256)
    *(float4*)&sW[t * 8] = *(const float4*)&W2f[(size_t)t * 8];
  half8 a2[2][4];
#pragma unroll
  for (int f = 0; f < 2; ++f) {
    const _Float16* tr = &sI[(w * 32 + f * 16 + col16) * 136 + q * 8];
#pragma unroll
    for (int kk = 0; kk < 4; ++kk) a2[f][kk] = *(const half8*)(tr + kk * 32);
  }
  __syncthreads();
#pragma unroll
  for (int n0 = 0; n0 < 8; ++n0) {
    f32x4 a0 = {0.f, 0.f, 0.f, 0.f}, a1 = {0.f, 0.f, 0.f, 0.f};
#pragma unroll
    for (int kk = 0; kk < 4; ++kk) {
      half8 b = *(const half8*)&sW[((n0 * 4 + kk) * 64 + lane) * 8];
      a0 = __builtin_amdgcn_mfma_f32_16x16x32_f16(a2[0][kk], b, a0, 0, 0, 0);
      a1 = __builtin_amdgcn_mfma_f32_16x16x32_f16(a2[1][kk], b, a1, 0, 0, 0);
    }
    int col = n0 * 16 + col16;
    float bb = b2[col];
#pragma unroll
    for (int r = 0; r < 4; ++r) {
      int r0 = m0 + w * 32 + q * 4 + r;
      int r1 = r0 + 16;
      if (r0 < N_NODES) O16[(size_t)r0 * D + col] = (_Float16)(a0[r] + bb);
      if (r1 < N_NODES) O16[(size_t)r1 * D + col] = (_Float16)(a1[r] + bb);
    }
  }
}

// fused head: pool 16 graphs into LDS, then 3-layer MLP (MFMA fp16)
__global__ __launch_bounds__(256) void k_head(
    const _Float16* __restrict__ x, const int* __restrict__ batch,
    const float* __restrict__ rdkit,
    const _Float16* __restrict__ W1f, const float* __restrict__ B1,
    const _Float16* __restrict__ W2f, const float* __restrict__ B2,
    const float* __restrict__ W3, const float* __restrict__ B3,
    float* __restrict__ out) {
  __shared__ _Float16 sHC[16 * 352];  // pooled+rdkit, fp16
  __shared__ _Float16 sH[16 * 520];   // h1
  __shared__ float sRed[4][16];
  int w = threadIdx.x >> 6, lane = threadIdx.x & 63;
  int m0 = blockIdx.x * 16;
  int col16 = lane & 15, q = lane >> 4;
#pragma unroll
  for (int gg = 0; gg < 4; ++gg) {
    int gl = w * 4 + gg;
    int g = m0 + gl;
    int lo = lbound(batch, N_NODES, g);
    int hi = lbound(batch, N_NODES, g + 1);
    float a0 = 0.f, a1 = 0.f;
    for (int i = lo; i < hi; ++i) {
      half2v v = *(const half2v*)&x[(size_t)i * D + lane * 2];
      a0 += (float)v.x; a1 += (float)v.y;
    }
    float inv = 1.f / fmaxf((float)(hi - lo), 1.f);
    sHC[gl * 352 + lane * 2] = (_Float16)(a0 * inv);
    sHC[gl * 352 + lane * 2 + 1] = (_Float16)(a1 * inv);
    for (int r = lane; r < RD; r += 64)
      sHC[gl * 352 + D + r] = (_Float16)rdkit[(size_t)g * RD + r];
    if (lane < 24) sHC[gl * 352 + 328 + lane] = (_Float16)0.f;
  }
  __syncthreads();
  {
    const _Float16* Ar = &sHC[col16 * 352 + q * 8];
    half8 afr[11];
#pragma unroll
    for (int kk = 0; kk < 11; ++kk) afr[kk] = *(const half8*)(Ar + kk * 32);
#pragma unroll
    for (int u = 0; u < 8; ++u) {
      int n0 = w * 8 + u;
      f32x4 acc = {0.f, 0.f, 0.f, 0.f};
#pragma unroll
      for (int kk = 0; kk < 11; ++kk) {
        half8 b = *(const half8*)&W1f[(size_t)((n0 * 11 + kk) * 64 + lane) * 8];
        acc = __builtin_amdgcn_mfma_f32_16x16x32_f16(afr[kk], b, acc, 0, 0, 0);
      }
      float bb = B1[n0 * 16 + col16];
#pragma unroll
      for (int r = 0; r < 4; ++r)
        sH[(q * 4 + r) * 520 + n0 * 16 + col16] = (_Float16)fmaxf(acc[r] + bb, 0.f);
    }
  }
  __syncthreads();
  half8 a2[16];
  {
    const _Float16* tr = &sH[col16 * 520 + q * 8];
#pragma unroll
    for (int kk = 0; kk < 16; ++kk) a2[kk] = *(const half8*)(tr + kk * 32);
  }
  f32x4 acc[4];
#pragma unroll
  for (int u = 0; u < 4; ++u) acc[u] = (f32x4){0.f, 0.f, 0.f, 0.f};
#pragma unroll
  for (int kk = 0; kk < 16; ++kk) {
#pragma unroll
    for (int u = 0; u < 4; ++u) {
      int n0 = w * 4 + u;
      half8 b = *(const half8*)&W2f[(size_t)((n0 * 16 + kk) * 64 + lane) * 8];
      acc[u] = __builtin_amdgcn_mfma_f32_16x16x32_f16(a2[kk], b, acc[u], 0, 0, 0);
    }
  }
  float p[4] = {0.f, 0.f, 0.f, 0.f};
#pragma unroll
  for (int u = 0; u < 4; ++u) {
    int col = (w * 4 + u) * 16 + col16;
    float bb = B2[col], w3 = W3[col];
#pragma unroll
    for (int r = 0; r < 4; ++r) p[r] += fmaxf(acc[u][r] + bb, 0.f) * w3;
  }
#pragma unroll
  for (int r = 0; r < 4; ++r) {
    p[r] += __shfl_xor(p[r], 1);
    p[r] += __shfl_xor(p[r], 2);
    p[r] += __shfl_xor(p[r], 4);
    p[r] += __shfl_xor(p[r], 8);
  }
  if (col16 == 0) {
#pragma unroll
    for (int r = 0; r < 4; ++r) sRed[w][q * 4 + r] = p[r];
  }
  __syncthreads();
  if (threadIdx.x < 16) {
    float s = sRed[0][threadIdx.x] + sRed[1][threadIdx.x] +
              sRed[2][threadIdx.x] + sRed[3][threadIdx.x];
    out[m0 + threadIdx.x] = s + B3[0];
  }
}

extern "C" void kernel_launch(void* const* d_in, const int* in_sizes, int n_in,
                              void* d_out, int out_size, void* d_ws, size_t ws_size,
                              hipStream_t stream) {
  const int* x_feat = (const int*)d_in[0];
  const int* ei = (const int*)d_in[1];
  const int* bondf = (const int*)d_in[2];
  const int* batch = (const int*)d_in[3];
  const float* rdkit = (const float*)d_in[4];
  const float* atom_emb = (const float*)d_in[5];
  const float* bond_emb = (const float*)d_in[6];
  const float* c1w1 = (const float*)d_in[7];
  const float* c1b1 = (const float*)d_in[8];
  const float* c1w2 = (const float*)d_in[9];
  const float* c1b2 = (const float*)d_in[10];
  const float* c2w1 = (const float*)d_in[11];
  const float* c2b1 = (const float*)d_in[12];
  const float* c2w2 = (const float*)d_in[13];
  const float* c2b2 = (const float*)d_in[14];
  const float* mw1 = (const float*)d_in[15];
  const float* mb1 = (const float*)d_in[16];
  const float* mw2 = (const float*)d_in[17];
  const float* mb2 = (const float*)d_in[18];
  const float* mw3 = (const float*)d_in[19];
  const float* mb3 = (const float*)d_in[20];
  float* out = (float*)d_out;

  char* ws = (char*)d_ws;
  size_t off = 0;
  auto alloc = [&](size_t bytes) {
    void* p = ws + off;
    off += (bytes + 255) & ~(size_t)255;
    return p;
  };
  _Float16* x16a = (_Float16*)alloc((size_t)N_NODES * D * 2);
  _Float16* x16b = (_Float16*)alloc((size_t)N_NODES * D * 2);
  _Float16* h16 = (_Float16*)alloc((size_t)N_NODES * D * 2);
  _Float16* x2_16 = (_Float16*)alloc((size_t)N_NODES * D * 2);
  int* deg = (int*)alloc((size_t)N_NODES * 4);
  int* cursor = (int*)alloc((size_t)N_NODES * 4);
  int* row_ptr = (int*)alloc((size_t)(N_NODES + 1) * 4);
  int* bsum = (int*)alloc(64 * 4);
  int* csr1 = (int*)alloc((size_t)N_EDGES * 4);
  unsigned short* dst16 = (unsigned short*)alloc((size_t)N_EDGES * 2);
  int* epack = (int*)alloc((size_t)N_EDGES * 4);
  _Float16* cWf = (_Float16*)alloc((size_t)4 * 2048 * 8 * 2);
  _Float16* W1f = (_Float16*)alloc((size_t)352 * 64 * 8 * 2);
  _Float16* W2f = (_Float16*)alloc((size_t)256 * 64 * 8 * 2);

  k_prep<<<256, 256, 0, stream>>>(c1w1, c1w2, c2w1, c2w2, mw1, mw2,
                                  cWf, W1f, W2f, deg);
  k_atom_count<<<6250 + 2500, 256, 0, stream>>>(x_feat, atom_emb, x16a,
                                                ei, bondf, deg, dst16, epack);

  int nb = (N_NODES + 1023) / 1024;
  k_scan_blocks<<<nb, 1024, 0, stream>>>(deg, row_ptr, bsum);
  k_scan_add<<<nb, 1024, 0, stream>>>(row_ptr, cursor, bsum);
  k_fill<<<(N_EDGES + 255) / 256, 256, 0, stream>>>(dst16, epack, cursor, csr1);

  int ctiles = (N_NODES + 127) / 128;  // 391
  // conv1
  k_agg<<<2048, 256, 0, stream>>>(x16a, row_ptr, csr1, bond_emb, h16);
  k_conv<<<ctiles, 256, 0, stream>>>(h16, cWf + 0 * 16384, c1b1,
                                     cWf + 1 * 16384, c1b2, x16b);
  // conv2
  k_agg<<<2048, 256, 0, stream>>>(x16b, row_ptr, csr1, bond_emb, h16);
  k_conv<<<ctiles, 256, 0, stream>>>(h16, cWf + 2 * 16384, c2b1,
                                     cWf + 3 * 16384, c2b2, x2_16);

  // fused pool + head MLP
  k_head<<<64, 256, 0, stream>>>(x2_16, batch, rdkit, W1f, mb1, W2f, mb2,
                                 mw3, mb3, out);

  (void)in_sizes; (void)n_in; (void)out_size; (void)ws_size;
}

// Round 12
// 312.959 us; speedup vs baseline: 4.3376x; 1.3025x over previous
//
#include <hip/hip_runtime.h>

#define N_NODES 50000
#define N_EDGES 640000
#define N_GRAPH 1024
#define D 128
#define RD 200

typedef __attribute__((ext_vector_type(4))) float f32x4;
typedef __attribute__((ext_vector_type(8))) float f32x8;
typedef __attribute__((ext_vector_type(2))) _Float16 half2v;
typedef __attribute__((ext_vector_type(4))) _Float16 half4;
typedef __attribute__((ext_vector_type(8))) _Float16 half8;

static __device__ __forceinline__ int lbound(const int* a, int n, int v) {
  int lo = 0, hi = n;
  while (lo < hi) { int m = (lo + hi) >> 1; if (a[m] < v) lo = m + 1; else hi = m; }
  return lo;
}

// ---- prep: weights -> fp16 fragment order; zero deg ----
__global__ void k_prep(const float* __restrict__ w0, const float* __restrict__ w1,
                       const float* __restrict__ w2, const float* __restrict__ w3,
                       const float* __restrict__ mw1, const float* __restrict__ mw2,
                       _Float16* __restrict__ cWf,   // [4][32*64*8]
                       _Float16* __restrict__ W1f,   // [352*64*8]
                       _Float16* __restrict__ W2f,   // [256*64*8]
                       int* __restrict__ deg) {
  int t = blockIdx.x * 256 + threadIdx.x;  // 0..65535
  if (t < N_NODES) deg[t] = 0;
  if (t < 8192) {
    int mat = t >> 11, r = t & 2047;
    int frag = r >> 6, lane = r & 63;
    int n0 = frag >> 2, kk = frag & 3;
    int n = n0 * 16 + (lane & 15);
    int kb = (lane >> 4) * 8 + kk * 32;
    const float* W = (mat == 0) ? w0 : (mat == 1) ? w1 : (mat == 2) ? w2 : w3;
    half8 o;
#pragma unroll
    for (int j = 0; j < 8; ++j) o[j] = (_Float16)W[(kb + j) * D + n];
    *(half8*)&cWf[((size_t)mat * 2048 + r) * 8] = o;
  } else if (t < 8192 + 22528) {
    int u = t - 8192;
    int frag = u >> 6, lane = u & 63;
    int n0 = frag / 11, kk = frag % 11;
    int n = n0 * 16 + (lane & 15);
    int kb = (lane >> 4) * 8 + kk * 32;
    half8 o;
#pragma unroll
    for (int j = 0; j < 8; ++j) {
      int k = kb + j;
      o[j] = (k < 328) ? (_Float16)mw1[k * 512 + n] : (_Float16)0.f;
    }
    *(half8*)&W1f[(size_t)u * 8] = o;
  } else if (t < 8192 + 22528 + 16384) {
    int u = t - 8192 - 22528;
    int frag = u >> 6, lane = u & 63;
    int n0 = frag >> 4, kk = frag & 15;
    int n = n0 * 16 + (lane & 15);
    int kb = (lane >> 4) * 8 + kk * 32;
    half8 o;
#pragma unroll
    for (int j = 0; j < 8; ++j) o[j] = (_Float16)mw2[(kb + j) * 256 + n];
    *(half8*)&W2f[(size_t)u * 8] = o;
  }
}

// fused: atom encoder (fp16) + degree count + dst16 + edge pack
__global__ void k_atom_count(const int* __restrict__ xf, const float* __restrict__ emb,
                             _Float16* __restrict__ x16,
                             const int* __restrict__ ei, const int* __restrict__ bondf,
                             int* __restrict__ deg,
                             unsigned short* __restrict__ dst16,
                             int* __restrict__ epack) {
  if (blockIdx.x < 6250) {
    int t = blockIdx.x * 256 + threadIdx.x;  // exactly 50000*32
    int node = t >> 5, c = (t & 31) << 2;
    float a0 = 0.f, a1 = 0.f, a2 = 0.f, a3 = 0.f;
#pragma unroll
    for (int f = 0; f < 9; ++f) {
      int v = xf[node * 9 + f];
      float4 e4 = *(const float4*)&emb[(f * 64 + v) * D + c];
      a0 += e4.x; a1 += e4.y; a2 += e4.z; a3 += e4.w;
    }
    half4 o;
    o.x = (_Float16)a0; o.y = (_Float16)a1; o.z = (_Float16)a2; o.w = (_Float16)a3;
    *(half4*)&x16[(size_t)node * D + c] = o;
  } else {
    int e = (blockIdx.x - 6250) * 256 + threadIdx.x;
    if (e < N_EDGES) {
      int d = ei[N_EDGES + e];
      atomicAdd(&deg[d], 1);
      dst16[e] = (unsigned short)d;
      int s = ei[e];
      int f0 = bondf[e * 3], f1 = bondf[e * 3 + 1], f2 = bondf[e * 3 + 2];
      epack[e] = s | (f0 << 16) | (f1 << 20) | (f2 << 24);
    }
  }
}

__global__ void k_scan_blocks(const int* __restrict__ deg, int* __restrict__ excl,
                              int* __restrict__ bsum) {
  __shared__ int sd[1024];
  int i = blockIdx.x * 1024 + threadIdx.x;
  int v = (i < N_NODES) ? deg[i] : 0;
  sd[threadIdx.x] = v;
  __syncthreads();
  for (int off = 1; off < 1024; off <<= 1) {
    int t = (threadIdx.x >= (unsigned)off) ? sd[threadIdx.x - off] : 0;
    __syncthreads();
    sd[threadIdx.x] += t;
    __syncthreads();
  }
  if (i < N_NODES) excl[i] = sd[threadIdx.x] - v;
  if (threadIdx.x == 1023) bsum[blockIdx.x] = sd[1023];
}

// add block-prefix; materialize cursor copy; row_ptr[N] = E
__global__ void k_scan_add(int* __restrict__ row_ptr, int* __restrict__ cursor,
                           const int* __restrict__ bsum) {
  int off = 0;
  for (int b = 0; b < blockIdx.x; ++b) off += bsum[b];
  int i = blockIdx.x * 1024 + threadIdx.x;
  if (i < N_NODES) {
    int r = row_ptr[i] + off;
    row_ptr[i] = r;
    cursor[i] = r;
  }
  if (blockIdx.x == 0 && threadIdx.x == 0) row_ptr[N_NODES] = N_EDGES;
}

// scatter fill: coalesced dst16/epack streams, atomic cursor, 4B csr writes
__global__ void k_fill(const unsigned short* __restrict__ dst16,
                       const int* __restrict__ epack,
                       int* __restrict__ cursor, int* __restrict__ csr1) {
  int e = blockIdx.x * 256 + threadIdx.x;
  if (e >= N_EDGES) return;
  int d = dst16[e];
  int pos = atomicAdd(&cursor[d], 1);
  csr1[pos] = epack[e];
}

// out[i] = x[i] + sum_j relu(x[src] + bond_emb_sum)
// packed csr (src|f<<16), fp16 packed math, static strided node assignment.
__global__ __launch_bounds__(256) void k_agg(
    const _Float16* __restrict__ x16, const int* __restrict__ row_ptr,
    const int* __restrict__ csr1, const float* __restrict__ bemb,
    _Float16* __restrict__ out) {
  __shared__ half8 sB[48 * 16];  // 12 KB fp16 bond table
  for (int t = threadIdx.x; t < 768; t += blockDim.x) {
    float4 v0 = *(const float4*)&bemb[t * 8];
    float4 v1 = *(const float4*)&bemb[t * 8 + 4];
    half8 h;
    h[0] = (_Float16)v0.x; h[1] = (_Float16)v0.y; h[2] = (_Float16)v0.z; h[3] = (_Float16)v0.w;
    h[4] = (_Float16)v1.x; h[5] = (_Float16)v1.y; h[6] = (_Float16)v1.z; h[7] = (_Float16)v1.w;
    sB[t] = h;
  }
  __syncthreads();
  int lane = threadIdx.x & 63;
  int quad = lane >> 4;
  int l15 = lane & 15;
  int c8 = l15 * 8;
  int wid = blockIdx.x * (blockDim.x >> 6) + (threadIdx.x >> 6);
  int nw = gridDim.x * (blockDim.x >> 6);
  for (int i = wid; i < N_NODES; i += nw) {
    f32x8 ac[2];
    ac[0] = (f32x8)(0.f); ac[1] = (f32x8)(0.f);
    int e0 = row_ptr[i], e1 = row_ptr[i + 1];
    int j = e0 + quad;
#define EDGE(u, jj)                                                          \
    {                                                                        \
      unsigned ed = (unsigned)csr1[jj];                                      \
      half8 xr = *(const half8*)&x16[(size_t)(ed & 0xFFFF) * D + c8];        \
      unsigned p = ed >> 16;                                                 \
      half8 m16 = (xr + sB[(p & 15) * 16 + l15]) +                           \
                  (sB[256 + ((p >> 4) & 15) * 16 + l15] +                    \
                   sB[512 + (p >> 8) * 16 + l15]);                           \
      f32x8 m = __builtin_convertvector(m16, f32x8);                         \
      _Pragma("unroll")                                                      \
      for (int tt = 0; tt < 8; ++tt) ac[u][tt] += fmaxf(m[tt], 0.f);         \
    }
    for (; j + 4 < e1; j += 8) { EDGE(0, j) EDGE(1, j + 4) }
    for (; j < e1; j += 4) EDGE(0, j)
#undef EDGE
    f32x8 acc = ac[0] + ac[1];
#pragma unroll
    for (int tt = 0; tt < 8; ++tt) {
      acc[tt] += __shfl_xor(acc[tt], 16);
      acc[tt] += __shfl_xor(acc[tt], 32);
    }
    if (quad == 0) {
      half8 sr = *(const half8*)&x16[(size_t)i * D + c8];
      f32x8 o = __builtin_convertvector(sr, f32x8) + acc;
      *(half8*)&out[(size_t)i * D + c8] = __builtin_convertvector(o, half8);
    }
  }
}

// fused GINE nn: out = relu(A@W1+b1)@W2+b2 ; fp16 MFMA, W staged in LDS.
__global__ __launch_bounds__(256) void k_conv(
    const _Float16* __restrict__ A,
    const _Float16* __restrict__ W1f, const float* __restrict__ b1,
    const _Float16* __restrict__ W2f, const float* __restrict__ b2,
    _Float16* __restrict__ O16) {
  __shared__ _Float16 sW[2048 * 8];
  __shared__ _Float16 sI[128 * 136];
  int tid = threadIdx.x, w = tid >> 6, lane = tid & 63;
  int m0 = blockIdx.x * 128;
  int col16 = lane & 15, q = lane >> 4;
  for (int t = tid; t < 2048; t += 256)
    *(float4*)&sW[t * 8] = *(const float4*)&W1f[(size_t)t * 8];
  half8 afr[2][4];
#pragma unroll
  for (int f = 0; f < 2; ++f) {
    int row = m0 + w * 32 + f * 16 + col16;
    if (row >= N_NODES) row = N_NODES - 1;
    const _Float16* Ar = A + (size_t)row * D + q * 8;
#pragma unroll
    for (int kk = 0; kk < 4; ++kk) afr[f][kk] = *(const half8*)(Ar + kk * 32);
  }
  __syncthreads();
#pragma unroll
  for (int n0 = 0; n0 < 8; ++n0) {
    f32x4 a0 = {0.f, 0.f, 0.f, 0.f}, a1 = {0.f, 0.f, 0.f, 0.f};
#pragma unroll
    for (int kk = 0; kk < 4; ++kk) {
      half8 b = *(const half8*)&sW[((n0 * 4 + kk) * 64 + lane) * 8];
      a0 = __builtin_amdgcn_mfma_f32_16x16x32_f16(afr[0][kk], b, a0, 0, 0, 0);
      a1 = __builtin_amdgcn_mfma_f32_16x16x32_f16(afr[1][kk], b, a1, 0, 0, 0);
    }
    float bb = b1[n0 * 16 + col16];
#pragma unroll
    for (int r = 0; r < 4; ++r) {
      sI[(w * 32 + q * 4 + r) * 136 + n0 * 16 + col16] = (_Float16)fmaxf(a0[r] + bb, 0.f);
      sI[(w * 32 + 16 + q * 4 + r) * 136 + n0 * 16 + col16] = (_Float16)fmaxf(a1[r] + bb, 0.f);
    }
  }
  __syncthreads();
  for (int t = tid; t < 2048; t += 256)
    *(float4*)&sW[t * 8] = *(const float4*)&W2f[(size_t)t * 8];
  half8 a2[2][4];
#pragma unroll
  for (int f = 0; f < 2; ++f) {
    const _Float16* tr = &sI[(w * 32 + f * 16 + col16) * 136 + q * 8];
#pragma unroll
    for (int kk = 0; kk < 4; ++kk) a2[f][kk] = *(const half8*)(tr + kk * 32);
  }
  __syncthreads();
#pragma unroll
  for (int n0 = 0; n0 < 8; ++n0) {
    f32x4 a0 = {0.f, 0.f, 0.f, 0.f}, a1 = {0.f, 0.f, 0.f, 0.f};
#pragma unroll
    for (int kk = 0; kk < 4; ++kk) {
      half8 b = *(const half8*)&sW[((n0 * 4 + kk) * 64 + lane) * 8];
      a0 = __builtin_amdgcn_mfma_f32_16x16x32_f16(a2[0][kk], b, a0, 0, 0, 0);
      a1 = __builtin_amdgcn_mfma_f32_16x16x32_f16(a2[1][kk], b, a1, 0, 0, 0);
    }
    int col = n0 * 16 + col16;
    float bb = b2[col];
#pragma unroll
    for (int r = 0; r < 4; ++r) {
      int r0 = m0 + w * 32 + q * 4 + r;
      int r1 = r0 + 16;
      if (r0 < N_NODES) O16[(size_t)r0 * D + col] = (_Float16)(a0[r] + bb);
      if (r1 < N_NODES) O16[(size_t)r1 * D + col] = (_Float16)(a1[r] + bb);
    }
  }
}

// mean-pool per graph -> hcat16[G][352]; also out[g] = b3 (mlp23 atomics add onto it)
__global__ __launch_bounds__(256) void k_pool(
    const _Float16* __restrict__ x, const int* __restrict__ batch,
    const float* __restrict__ rdkit, _Float16* __restrict__ hcat,
    const float* __restrict__ B3, float* __restrict__ out) {
  int g = blockIdx.x * 4 + (threadIdx.x >> 6);
  if (g >= N_GRAPH) return;
  int lane = threadIdx.x & 63;
  int half_ = lane >> 5;
  int c4 = (lane & 31) * 4;
  int lo = lbound(batch, N_NODES, g);
  int hi = lbound(batch, N_NODES, g + 1);
  f32x4 a = {0.f, 0.f, 0.f, 0.f};
  for (int i = lo + half_; i < hi; i += 2) {
    half4 v = *(const half4*)&x[(size_t)i * D + c4];
    a += __builtin_convertvector(v, f32x4);
  }
#pragma unroll
  for (int t = 0; t < 4; ++t) a[t] += __shfl_xor(a[t], 32);
  float inv = 1.f / fmaxf((float)(hi - lo), 1.f);
  if (half_ == 0) {
    half4 o;
    o.x = (_Float16)(a[0] * inv); o.y = (_Float16)(a[1] * inv);
    o.z = (_Float16)(a[2] * inv); o.w = (_Float16)(a[3] * inv);
    *(half4*)&hcat[(size_t)g * 352 + c4] = o;
  }
  for (int r = lane; r < RD; r += 64)
    hcat[(size_t)g * 352 + D + r] = (_Float16)rdkit[(size_t)g * RD + r];
  if (lane < 24) hcat[(size_t)g * 352 + 328 + lane] = (_Float16)0.f;
  if (lane == 0) out[g] = B3[0];
}

// h1 = relu(hcat16 @ W1 + b1); wave = (mtile, 16-col group) -> 2048 waves / 512 blocks
__global__ __launch_bounds__(256) void k_mlp1(
    const _Float16* __restrict__ A, const _Float16* __restrict__ W1f,
    const float* __restrict__ B, _Float16* __restrict__ O) {
  int w = threadIdx.x >> 6, lane = threadIdx.x & 63;
  int gid = blockIdx.x * 4 + w;  // 0..2047
  int mt = gid >> 5, n0 = gid & 31;
  int col16 = lane & 15, q = lane >> 4;
  const _Float16* Ar = A + (size_t)(mt * 16 + col16) * 352 + q * 8;
  f32x4 acc = {0.f, 0.f, 0.f, 0.f};
#pragma unroll
  for (int kk = 0; kk < 11; ++kk) {
    half8 a = *(const half8*)(Ar + kk * 32);
    half8 b = *(const half8*)&W1f[(size_t)((n0 * 11 + kk) * 64 + lane) * 8];
    acc = __builtin_amdgcn_mfma_f32_16x16x32_f16(a, b, acc, 0, 0, 0);
  }
  int col = n0 * 16 + col16;
  float bb = B[col];
#pragma unroll
  for (int r = 0; r < 4; ++r) {
    int row = mt * 16 + q * 4 + r;
    O[(size_t)row * 512 + col] = (_Float16)fmaxf(acc[r] + bb, 0.f);
  }
}

// out[g] += sum_cols relu(h1@W2+b2)*w3 ; wave = (mtile, 16-col group) -> 1024 waves / 256 blocks
__global__ __launch_bounds__(256) void k_mlp23(
    const _Float16* __restrict__ A, const _Float16* __restrict__ W2f,
    const float* __restrict__ B2, const float* __restrict__ W3,
    float* __restrict__ out) {
  int w = threadIdx.x >> 6, lane = threadIdx.x & 63;
  int gid = blockIdx.x * 4 + w;  // 0..1023
  int mt = gid >> 4, n0 = gid & 15;
  int col16 = lane & 15, q = lane >> 4;
  const _Float16* Ar = A + (size_t)(mt * 16 + col16) * 512 + q * 8;
  f32x4 acc = {0.f, 0.f, 0.f, 0.f};
#pragma unroll
  for (int kk = 0; kk < 16; ++kk) {
    half8 a = *(const half8*)(Ar + kk * 32);
    half8 b = *(const half8*)&W2f[(size_t)((n0 * 16 + kk) * 64 + lane) * 8];
    acc = __builtin_amdgcn_mfma_f32_16x16x32_f16(a, b, acc, 0, 0, 0);
  }
  int col = n0 * 16 + col16;
  float bb = B2[col], w3 = W3[col];
  float p[4];
#pragma unroll
  for (int r = 0; r < 4; ++r) p[r] = fmaxf(acc[r] + bb, 0.f) * w3;
#pragma unroll
  for (int r = 0; r < 4; ++r) {
    p[r] += __shfl_xor(p[r], 1);
    p[r] += __shfl_xor(p[r], 2);
    p[r] += __shfl_xor(p[r], 4);
    p[r] += __shfl_xor(p[r], 8);
  }
  if (col16 == 0) {
#pragma unroll
    for (int r = 0; r < 4; ++r)
      atomicAdd(&out[mt * 16 + q * 4 + r], p[r]);
  }
}

extern "C" void kernel_launch(void* const* d_in, const int* in_sizes, int n_in,
                              void* d_out, int out_size, void* d_ws, size_t ws_size,
                              hipStream_t stream) {
  const int* x_feat = (const int*)d_in[0];
  const int* ei = (const int*)d_in[1];
  const int* bondf = (const int*)d_in[2];
  const int* batch = (const int*)d_in[3];
  const float* rdkit = (const float*)d_in[4];
  const float* atom_emb = (const float*)d_in[5];
  const float* bond_emb = (const float*)d_in[6];
  const float* c1w1 = (const float*)d_in[7];
  const float* c1b1 = (const float*)d_in[8];
  const float* c1w2 = (const float*)d_in[9];
  const float* c1b2 = (const float*)d_in[10];
  const float* c2w1 = (const float*)d_in[11];
  const float* c2b1 = (const float*)d_in[12];
  const float* c2w2 = (const float*)d_in[13];
  const float* c2b2 = (const float*)d_in[14];
  const float* mw1 = (const float*)d_in[15];
  const float* mb1 = (const float*)d_in[16];
  const float* mw2 = (const float*)d_in[17];
  const float* mb2 = (const float*)d_in[18];
  const float* mw3 = (const float*)d_in[19];
  const float* mb3 = (const float*)d_in[20];
  float* out = (float*)d_out;

  char* ws = (char*)d_ws;
  size_t off = 0;
  auto alloc = [&](size_t bytes) {
    void* p = ws + off;
    off += (bytes + 255) & ~(size_t)255;
    return p;
  };
  _Float16* x16a = (_Float16*)alloc((size_t)N_NODES * D * 2);
  _Float16* x16b = (_Float16*)alloc((size_t)N_NODES * D * 2);
  _Float16* h16 = (_Float16*)alloc((size_t)N_NODES * D * 2);
  _Float16* x2_16 = (_Float16*)alloc((size_t)N_NODES * D * 2);
  int* deg = (int*)alloc((size_t)N_NODES * 4);
  int* cursor = (int*)alloc((size_t)N_NODES * 4);
  int* row_ptr = (int*)alloc((size_t)(N_NODES + 1) * 4);
  int* bsum = (int*)alloc(64 * 4);
  int* csr1 = (int*)alloc((size_t)N_EDGES * 4);
  unsigned short* dst16 = (unsigned short*)alloc((size_t)N_EDGES * 2);
  int* epack = (int*)alloc((size_t)N_EDGES * 4);
  _Float16* hcat16 = (_Float16*)alloc((size_t)N_GRAPH * 352 * 2);
  _Float16* h1buf = (_Float16*)alloc((size_t)N_GRAPH * 512 * 2);
  _Float16* cWf = (_Float16*)alloc((size_t)4 * 2048 * 8 * 2);
  _Float16* W1f = (_Float16*)alloc((size_t)352 * 64 * 8 * 2);
  _Float16* W2f = (_Float16*)alloc((size_t)256 * 64 * 8 * 2);

  k_prep<<<256, 256, 0, stream>>>(c1w1, c1w2, c2w1, c2w2, mw1, mw2,
                                  cWf, W1f, W2f, deg);
  k_atom_count<<<6250 + 2500, 256, 0, stream>>>(x_feat, atom_emb, x16a,
                                                ei, bondf, deg, dst16, epack);

  int nb = (N_NODES + 1023) / 1024;
  k_scan_blocks<<<nb, 1024, 0, stream>>>(deg, row_ptr, bsum);
  k_scan_add<<<nb, 1024, 0, stream>>>(row_ptr, cursor, bsum);
  k_fill<<<(N_EDGES + 255) / 256, 256, 0, stream>>>(dst16, epack, cursor, csr1);

  int ctiles = (N_NODES + 127) / 128;  // 391
  // conv1
  k_agg<<<2048, 256, 0, stream>>>(x16a, row_ptr, csr1, bond_emb, h16);
  k_conv<<<ctiles, 256, 0, stream>>>(h16, cWf + 0 * 16384, c1b1,
                                     cWf + 1 * 16384, c1b2, x16b);
  // conv2
  k_agg<<<2048, 256, 0, stream>>>(x16b, row_ptr, csr1, bond_emb, h16);
  k_conv<<<ctiles, 256, 0, stream>>>(h16, cWf + 2 * 16384, c2b1,
                                     cWf + 3 * 16384, c2b2, x2_16);

  // pool (also inits out = b3) + high-parallelism head
  k_pool<<<N_GRAPH / 4, 256, 0, stream>>>(x2_16, batch, rdkit, hcat16, mb3, out);
  k_mlp1<<<512, 256, 0, stream>>>(hcat16, W1f, mb1, h1buf);
  k_mlp23<<<256, 256, 0, stream>>>(h1buf, W2f, mb2, mw3, out);

  (void)in_sizes; (void)n_in; (void)out_size; (void)ws_size;
}

// Round 13
// 295.130 us; speedup vs baseline: 4.5996x; 1.0604x over previous
//
#include <hip/hip_runtime.h>

#define N_NODES 50000
#define N_EDGES 640000
#define N_GRAPH 1024
#define D 128
#define RD 200

typedef __attribute__((ext_vector_type(4))) float f32x4;
typedef __attribute__((ext_vector_type(8))) float f32x8;
typedef __attribute__((ext_vector_type(2))) _Float16 half2v;
typedef __attribute__((ext_vector_type(4))) _Float16 half4;
typedef __attribute__((ext_vector_type(8))) _Float16 half8;

static __device__ __forceinline__ int lbound(const int* a, int n, int v) {
  int lo = 0, hi = n;
  while (lo < hi) { int m = (lo + hi) >> 1; if (a[m] < v) lo = m + 1; else hi = m; }
  return lo;
}

// ---- prep: weights -> fp16 fragment order; zero deg ----
__global__ void k_prep(const float* __restrict__ w0, const float* __restrict__ w1,
                       const float* __restrict__ w2, const float* __restrict__ w3,
                       const float* __restrict__ mw1, const float* __restrict__ mw2,
                       _Float16* __restrict__ cWf,   // [4][32*64*8]
                       _Float16* __restrict__ W1f,   // [352*64*8]
                       _Float16* __restrict__ W2f,   // [256*64*8]
                       int* __restrict__ deg) {
  int t = blockIdx.x * 256 + threadIdx.x;  // 0..65535
  if (t < N_NODES) deg[t] = 0;
  if (t < 8192) {
    int mat = t >> 11, r = t & 2047;
    int frag = r >> 6, lane = r & 63;
    int n0 = frag >> 2, kk = frag & 3;
    int n = n0 * 16 + (lane & 15);
    int kb = (lane >> 4) * 8 + kk * 32;
    const float* W = (mat == 0) ? w0 : (mat == 1) ? w1 : (mat == 2) ? w2 : w3;
    half8 o;
#pragma unroll
    for (int j = 0; j < 8; ++j) o[j] = (_Float16)W[(kb + j) * D + n];
    *(half8*)&cWf[((size_t)mat * 2048 + r) * 8] = o;
  } else if (t < 8192 + 22528) {
    int u = t - 8192;
    int frag = u >> 6, lane = u & 63;
    int n0 = frag / 11, kk = frag % 11;
    int n = n0 * 16 + (lane & 15);
    int kb = (lane >> 4) * 8 + kk * 32;
    half8 o;
#pragma unroll
    for (int j = 0; j < 8; ++j) {
      int k = kb + j;
      o[j] = (k < 328) ? (_Float16)mw1[k * 512 + n] : (_Float16)0.f;
    }
    *(half8*)&W1f[(size_t)u * 8] = o;
  } else if (t < 8192 + 22528 + 16384) {
    int u = t - 8192 - 22528;
    int frag = u >> 6, lane = u & 63;
    int n0 = frag >> 4, kk = frag & 15;
    int n = n0 * 16 + (lane & 15);
    int kb = (lane >> 4) * 8 + kk * 32;
    half8 o;
#pragma unroll
    for (int j = 0; j < 8; ++j) o[j] = (_Float16)mw2[(kb + j) * 256 + n];
    *(half8*)&W2f[(size_t)u * 8] = o;
  }
}

// fused: atom encoder (fp16) + degree count (rank captured!) + edge pack
__global__ void k_atom_count(const int* __restrict__ xf, const float* __restrict__ emb,
                             _Float16* __restrict__ x16,
                             const int* __restrict__ ei, const int* __restrict__ bondf,
                             int* __restrict__ deg,
                             int* __restrict__ dr,      // d | rank<<16
                             int* __restrict__ epack) {
  if (blockIdx.x < 6250) {
    int t = blockIdx.x * 256 + threadIdx.x;  // exactly 50000*32
    int node = t >> 5, c = (t & 31) << 2;
    float a0 = 0.f, a1 = 0.f, a2 = 0.f, a3 = 0.f;
#pragma unroll
    for (int f = 0; f < 9; ++f) {
      int v = xf[node * 9 + f];
      float4 e4 = *(const float4*)&emb[(f * 64 + v) * D + c];
      a0 += e4.x; a1 += e4.y; a2 += e4.z; a3 += e4.w;
    }
    half4 o;
    o.x = (_Float16)a0; o.y = (_Float16)a1; o.z = (_Float16)a2; o.w = (_Float16)a3;
    *(half4*)&x16[(size_t)node * D + c] = o;
  } else {
    int e = (blockIdx.x - 6250) * 256 + threadIdx.x;
    if (e < N_EDGES) {
      int d = ei[N_EDGES + e];
      int rank = atomicAdd(&deg[d], 1);  // rank among same-dst edges
      dr[e] = d | (rank << 16);
      int s = ei[e];
      int f0 = bondf[e * 3], f1 = bondf[e * 3 + 1], f2 = bondf[e * 3 + 2];
      epack[e] = s | (f0 << 16) | (f1 << 20) | (f2 << 24);
    }
  }
}

__global__ void k_scan_blocks(const int* __restrict__ deg, int* __restrict__ excl,
                              int* __restrict__ bsum) {
  __shared__ int sd[1024];
  int i = blockIdx.x * 1024 + threadIdx.x;
  int v = (i < N_NODES) ? deg[i] : 0;
  sd[threadIdx.x] = v;
  __syncthreads();
  for (int off = 1; off < 1024; off <<= 1) {
    int t = (threadIdx.x >= (unsigned)off) ? sd[threadIdx.x - off] : 0;
    __syncthreads();
    sd[threadIdx.x] += t;
    __syncthreads();
  }
  if (i < N_NODES) excl[i] = sd[threadIdx.x] - v;
  if (threadIdx.x == 1023) bsum[blockIdx.x] = sd[1023];
}

// add block-prefix; row_ptr[N] = E
__global__ void k_scan_add(int* __restrict__ row_ptr, const int* __restrict__ bsum) {
  int off = 0;
  for (int b = 0; b < blockIdx.x; ++b) off += bsum[b];
  int i = blockIdx.x * 1024 + threadIdx.x;
  if (i < N_NODES) row_ptr[i] += off;
  if (blockIdx.x == 0 && threadIdx.x == 0) row_ptr[N_NODES] = N_EDGES;
}

// atomic-free fill: pos = row_ptr[d] + rank (rank precomputed in k_atom_count)
__global__ void k_fill(const int* __restrict__ dr, const int* __restrict__ epack,
                       const int* __restrict__ row_ptr, int* __restrict__ csr1) {
  int e = blockIdx.x * 256 + threadIdx.x;
  if (e >= N_EDGES) return;
  int v = dr[e];
  int d = v & 0xFFFF, rank = v >> 16;
  csr1[row_ptr[d] + rank] = epack[e];
}

// out[i] = x[i] + sum_j relu(x[src] + bond_emb_sum)
// packed csr (src|f<<16), fp16 packed math, static strided node assignment.
__global__ __launch_bounds__(256) void k_agg(
    const _Float16* __restrict__ x16, const int* __restrict__ row_ptr,
    const int* __restrict__ csr1, const float* __restrict__ bemb,
    _Float16* __restrict__ out) {
  __shared__ half8 sB[48 * 16];  // 12 KB fp16 bond table
  for (int t = threadIdx.x; t < 768; t += blockDim.x) {
    float4 v0 = *(const float4*)&bemb[t * 8];
    float4 v1 = *(const float4*)&bemb[t * 8 + 4];
    half8 h;
    h[0] = (_Float16)v0.x; h[1] = (_Float16)v0.y; h[2] = (_Float16)v0.z; h[3] = (_Float16)v0.w;
    h[4] = (_Float16)v1.x; h[5] = (_Float16)v1.y; h[6] = (_Float16)v1.z; h[7] = (_Float16)v1.w;
    sB[t] = h;
  }
  __syncthreads();
  int lane = threadIdx.x & 63;
  int quad = lane >> 4;
  int l15 = lane & 15;
  int c8 = l15 * 8;
  int wid = blockIdx.x * (blockDim.x >> 6) + (threadIdx.x >> 6);
  int nw = gridDim.x * (blockDim.x >> 6);
  for (int i = wid; i < N_NODES; i += nw) {
    f32x8 ac[2];
    ac[0] = (f32x8)(0.f); ac[1] = (f32x8)(0.f);
    int e0 = row_ptr[i], e1 = row_ptr[i + 1];
    int j = e0 + quad;
#define EDGE(u, jj)                                                          \
    {                                                                        \
      unsigned ed = (unsigned)csr1[jj];                                      \
      half8 xr = *(const half8*)&x16[(size_t)(ed & 0xFFFF) * D + c8];        \
      unsigned p = ed >> 16;                                                 \
      half8 m16 = (xr + sB[(p & 15) * 16 + l15]) +                           \
                  (sB[256 + ((p >> 4) & 15) * 16 + l15] +                    \
                   sB[512 + (p >> 8) * 16 + l15]);                           \
      f32x8 m = __builtin_convertvector(m16, f32x8);                         \
      _Pragma("unroll")                                                      \
      for (int tt = 0; tt < 8; ++tt) ac[u][tt] += fmaxf(m[tt], 0.f);         \
    }
    for (; j + 4 < e1; j += 8) { EDGE(0, j) EDGE(1, j + 4) }
    for (; j < e1; j += 4) EDGE(0, j)
#undef EDGE
    f32x8 acc = ac[0] + ac[1];
#pragma unroll
    for (int tt = 0; tt < 8; ++tt) {
      acc[tt] += __shfl_xor(acc[tt], 16);
      acc[tt] += __shfl_xor(acc[tt], 32);
    }
    if (quad == 0) {
      half8 sr = *(const half8*)&x16[(size_t)i * D + c8];
      f32x8 o = __builtin_convertvector(sr, f32x8) + acc;
      *(half8*)&out[(size_t)i * D + c8] = __builtin_convertvector(o, half8);
    }
  }
}

// fused GINE nn: out = relu(A@W1+b1)@W2+b2 ; fp16 MFMA, W staged in LDS.
__global__ __launch_bounds__(256) void k_conv(
    const _Float16* __restrict__ A,
    const _Float16* __restrict__ W1f, const float* __restrict__ b1,
    const _Float16* __restrict__ W2f, const float* __restrict__ b2,
    _Float16* __restrict__ O16) {
  __shared__ _Float16 sW[2048 * 8];
  __shared__ _Float16 sI[128 * 136];
  int tid = threadIdx.x, w = tid >> 6, lane = tid & 63;
  int m0 = blockIdx.x * 128;
  int col16 = lane & 15, q = lane >> 4;
  for (int t = tid; t < 2048; t += 256)
    *(float4*)&sW[t * 8] = *(const float4*)&W1f[(size_t)t * 8];
  half8 afr[2][4];
#pragma unroll
  for (int f = 0; f < 2; ++f) {
    int row = m0 + w * 32 + f * 16 + col16;
    if (row >= N_NODES) row = N_NODES - 1;
    const _Float16* Ar = A + (size_t)row * D + q * 8;
#pragma unroll
    for (int kk = 0; kk < 4; ++kk) afr[f][kk] = *(const half8*)(Ar + kk * 32);
  }
  __syncthreads();
#pragma unroll
  for (int n0 = 0; n0 < 8; ++n0) {
    f32x4 a0 = {0.f, 0.f, 0.f, 0.f}, a1 = {0.f, 0.f, 0.f, 0.f};
#pragma unroll
    for (int kk = 0; kk < 4; ++kk) {
      half8 b = *(const half8*)&sW[((n0 * 4 + kk) * 64 + lane) * 8];
      a0 = __builtin_amdgcn_mfma_f32_16x16x32_f16(afr[0][kk], b, a0, 0, 0, 0);
      a1 = __builtin_amdgcn_mfma_f32_16x16x32_f16(afr[1][kk], b, a1, 0, 0, 0);
    }
    float bb = b1[n0 * 16 + col16];
#pragma unroll
    for (int r = 0; r < 4; ++r) {
      sI[(w * 32 + q * 4 + r) * 136 + n0 * 16 + col16] = (_Float16)fmaxf(a0[r] + bb, 0.f);
      sI[(w * 32 + 16 + q * 4 + r) * 136 + n0 * 16 + col16] = (_Float16)fmaxf(a1[r] + bb, 0.f);
    }
  }
  __syncthreads();
  for (int t = tid; t < 2048; t += 256)
    *(float4*)&sW[t * 8] = *(const float4*)&W2f[(size_t)t * 8];
  half8 a2[2][4];
#pragma unroll
  for (int f = 0; f < 2; ++f) {
    const _Float16* tr = &sI[(w * 32 + f * 16 + col16) * 136 + q * 8];
#pragma unroll
    for (int kk = 0; kk < 4; ++kk) a2[f][kk] = *(const half8*)(tr + kk * 32);
  }
  __syncthreads();
#pragma unroll
  for (int n0 = 0; n0 < 8; ++n0) {
    f32x4 a0 = {0.f, 0.f, 0.f, 0.f}, a1 = {0.f, 0.f, 0.f, 0.f};
#pragma unroll
    for (int kk = 0; kk < 4; ++kk) {
      half8 b = *(const half8*)&sW[((n0 * 4 + kk) * 64 + lane) * 8];
      a0 = __builtin_amdgcn_mfma_f32_16x16x32_f16(a2[0][kk], b, a0, 0, 0, 0);
      a1 = __builtin_amdgcn_mfma_f32_16x16x32_f16(a2[1][kk], b, a1, 0, 0, 0);
    }
    int col = n0 * 16 + col16;
    float bb = b2[col];
#pragma unroll
    for (int r = 0; r < 4; ++r) {
      int r0 = m0 + w * 32 + q * 4 + r;
      int r1 = r0 + 16;
      if (r0 < N_NODES) O16[(size_t)r0 * D + col] = (_Float16)(a0[r] + bb);
      if (r1 < N_NODES) O16[(size_t)r1 * D + col] = (_Float16)(a1[r] + bb);
    }
  }
}

// mean-pool per graph -> hcat16[G][352]; also out[g] = b3 (mlp23 atomics add onto it)
__global__ __launch_bounds__(256) void k_pool(
    const _Float16* __restrict__ x, const int* __restrict__ batch,
    const float* __restrict__ rdkit, _Float16* __restrict__ hcat,
    const float* __restrict__ B3, float* __restrict__ out) {
  int g = blockIdx.x * 4 + (threadIdx.x >> 6);
  if (g >= N_GRAPH) return;
  int lane = threadIdx.x & 63;
  int half_ = lane >> 5;
  int c4 = (lane & 31) * 4;
  int lo = lbound(batch, N_NODES, g);
  int hi = lbound(batch, N_NODES, g + 1);
  f32x4 a = {0.f, 0.f, 0.f, 0.f};
  for (int i = lo + half_; i < hi; i += 2) {
    half4 v = *(const half4*)&x[(size_t)i * D + c4];
    a += __builtin_convertvector(v, f32x4);
  }
#pragma unroll
  for (int t = 0; t < 4; ++t) a[t] += __shfl_xor(a[t], 32);
  float inv = 1.f / fmaxf((float)(hi - lo), 1.f);
  if (half_ == 0) {
    half4 o;
    o.x = (_Float16)(a[0] * inv); o.y = (_Float16)(a[1] * inv);
    o.z = (_Float16)(a[2] * inv); o.w = (_Float16)(a[3] * inv);
    *(half4*)&hcat[(size_t)g * 352 + c4] = o;
  }
  for (int r = lane; r < RD; r += 64)
    hcat[(size_t)g * 352 + D + r] = (_Float16)rdkit[(size_t)g * RD + r];
  if (lane < 24) hcat[(size_t)g * 352 + 328 + lane] = (_Float16)0.f;
  if (lane == 0) out[g] = B3[0];
}

// h1 = relu(hcat16 @ W1 + b1); wave = (mtile, 16-col group) -> 2048 waves / 512 blocks
__global__ __launch_bounds__(256) void k_mlp1(
    const _Float16* __restrict__ A, const _Float16* __restrict__ W1f,
    const float* __restrict__ B, _Float16* __restrict__ O) {
  int w = threadIdx.x >> 6, lane = threadIdx.x & 63;
  int gid = blockIdx.x * 4 + w;  // 0..2047
  int mt = gid >> 5, n0 = gid & 31;
  int col16 = lane & 15, q = lane >> 4;
  const _Float16* Ar = A + (size_t)(mt * 16 + col16) * 352 + q * 8;
  f32x4 acc = {0.f, 0.f, 0.f, 0.f};
#pragma unroll
  for (int kk = 0; kk < 11; ++kk) {
    half8 a = *(const half8*)(Ar + kk * 32);
    half8 b = *(const half8*)&W1f[(size_t)((n0 * 11 + kk) * 64 + lane) * 8];
    acc = __builtin_amdgcn_mfma_f32_16x16x32_f16(a, b, acc, 0, 0, 0);
  }
  int col = n0 * 16 + col16;
  float bb = B[col];
#pragma unroll
  for (int r = 0; r < 4; ++r) {
    int row = mt * 16 + q * 4 + r;
    O[(size_t)row * 512 + col] = (_Float16)fmaxf(acc[r] + bb, 0.f);
  }
}

// out[g] += sum_cols relu(h1@W2+b2)*w3 ; wave = (mtile, 16-col group) -> 1024 waves / 256 blocks
__global__ __launch_bounds__(256) void k_mlp23(
    const _Float16* __restrict__ A, const _Float16* __restrict__ W2f,
    const float* __restrict__ B2, const float* __restrict__ W3,
    float* __restrict__ out) {
  int w = threadIdx.x >> 6, lane = threadIdx.x & 63;
  int gid = blockIdx.x * 4 + w;  // 0..1023
  int mt = gid >> 4, n0 = gid & 15;
  int col16 = lane & 15, q = lane >> 4;
  const _Float16* Ar = A + (size_t)(mt * 16 + col16) * 512 + q * 8;
  f32x4 acc = {0.f, 0.f, 0.f, 0.f};
#pragma unroll
  for (int kk = 0; kk < 16; ++kk) {
    half8 a = *(const half8*)(Ar + kk * 32);
    half8 b = *(const half8*)&W2f[(size_t)((n0 * 16 + kk) * 64 + lane) * 8];
    acc = __builtin_amdgcn_mfma_f32_16x16x32_f16(a, b, acc, 0, 0, 0);
  }
  int col = n0 * 16 + col16;
  float bb = B2[col], w3 = W3[col];
  float p[4];
#pragma unroll
  for (int r = 0; r < 4; ++r) p[r] = fmaxf(acc[r] + bb, 0.f) * w3;
#pragma unroll
  for (int r = 0; r < 4; ++r) {
    p[r] += __shfl_xor(p[r], 1);
    p[r] += __shfl_xor(p[r], 2);
    p[r] += __shfl_xor(p[r], 4);
    p[r] += __shfl_xor(p[r], 8);
  }
  if (col16 == 0) {
#pragma unroll
    for (int r = 0; r < 4; ++r)
      atomicAdd(&out[mt * 16 + q * 4 + r], p[r]);
  }
}

extern "C" void kernel_launch(void* const* d_in, const int* in_sizes, int n_in,
                              void* d_out, int out_size, void* d_ws, size_t ws_size,
                              hipStream_t stream) {
  const int* x_feat = (const int*)d_in[0];
  const int* ei = (const int*)d_in[1];
  const int* bondf = (const int*)d_in[2];
  const int* batch = (const int*)d_in[3];
  const float* rdkit = (const float*)d_in[4];
  const float* atom_emb = (const float*)d_in[5];
  const float* bond_emb = (const float*)d_in[6];
  const float* c1w1 = (const float*)d_in[7];
  const float* c1b1 = (const float*)d_in[8];
  const float* c1w2 = (const float*)d_in[9];
  const float* c1b2 = (const float*)d_in[10];
  const float* c2w1 = (const float*)d_in[11];
  const float* c2b1 = (const float*)d_in[12];
  const float* c2w2 = (const float*)d_in[13];
  const float* c2b2 = (const float*)d_in[14];
  const float* mw1 = (const float*)d_in[15];
  const float* mb1 = (const float*)d_in[16];
  const float* mw2 = (const float*)d_in[17];
  const float* mb2 = (const float*)d_in[18];
  const float* mw3 = (const float*)d_in[19];
  const float* mb3 = (const float*)d_in[20];
  float* out = (float*)d_out;

  char* ws = (char*)d_ws;
  size_t off = 0;
  auto alloc = [&](size_t bytes) {
    void* p = ws + off;
    off += (bytes + 255) & ~(size_t)255;
    return p;
  };
  _Float16* x16a = (_Float16*)alloc((size_t)N_NODES * D * 2);
  _Float16* x16b = (_Float16*)alloc((size_t)N_NODES * D * 2);
  _Float16* h16 = (_Float16*)alloc((size_t)N_NODES * D * 2);
  _Float16* x2_16 = (_Float16*)alloc((size_t)N_NODES * D * 2);
  int* deg = (int*)alloc((size_t)N_NODES * 4);
  int* row_ptr = (int*)alloc((size_t)(N_NODES + 1) * 4);
  int* bsum = (int*)alloc(64 * 4);
  int* csr1 = (int*)alloc((size_t)N_EDGES * 4);
  int* dr = (int*)alloc((size_t)N_EDGES * 4);
  int* epack = (int*)alloc((size_t)N_EDGES * 4);
  _Float16* hcat16 = (_Float16*)alloc((size_t)N_GRAPH * 352 * 2);
  _Float16* h1buf = (_Float16*)alloc((size_t)N_GRAPH * 512 * 2);
  _Float16* cWf = (_Float16*)alloc((size_t)4 * 2048 * 8 * 2);
  _Float16* W1f = (_Float16*)alloc((size_t)352 * 64 * 8 * 2);
  _Float16* W2f = (_Float16*)alloc((size_t)256 * 64 * 8 * 2);

  k_prep<<<256, 256, 0, stream>>>(c1w1, c1w2, c2w1, c2w2, mw1, mw2,
                                  cWf, W1f, W2f, deg);
  k_atom_count<<<6250 + 2500, 256, 0, stream>>>(x_feat, atom_emb, x16a,
                                                ei, bondf, deg, dr, epack);

  int nb = (N_NODES + 1023) / 1024;
  k_scan_blocks<<<nb, 1024, 0, stream>>>(deg, row_ptr, bsum);
  k_scan_add<<<nb, 1024, 0, stream>>>(row_ptr, bsum);
  k_fill<<<(N_EDGES + 255) / 256, 256, 0, stream>>>(dr, epack, row_ptr, csr1);

  int ctiles = (N_NODES + 127) / 128;  // 391
  // conv1
  k_agg<<<2048, 256, 0, stream>>>(x16a, row_ptr, csr1, bond_emb, h16);
  k_conv<<<ctiles, 256, 0, stream>>>(h16, cWf + 0 * 16384, c1b1,
                                     cWf + 1 * 16384, c1b2, x16b);
  // conv2
  k_agg<<<2048, 256, 0, stream>>>(x16b, row_ptr, csr1, bond_emb, h16);
  k_conv<<<ctiles, 256, 0, stream>>>(h16, cWf + 2 * 16384, c2b1,
                                     cWf + 3 * 16384, c2b2, x2_16);

  // pool (also inits out = b3) + high-parallelism head
  k_pool<<<N_GRAPH / 4, 256, 0, stream>>>(x2_16, batch, rdkit, hcat16, mb3, out);
  k_mlp1<<<512, 256, 0, stream>>>(hcat16, W1f, mb1, h1buf);
  k_mlp23<<<256, 256, 0, stream>>>(h1buf, W2f, mb2, mw3, out);

  (void)in_sizes; (void)n_in; (void)out_size; (void)ws_size;
}

// Round 14
// 283.868 us; speedup vs baseline: 4.7821x; 1.0397x over previous
//
#include <hip/hip_runtime.h>

#define N_NODES 50000
#define N_EDGES 640000
#define N_GRAPH 1024
#define D 128
#define RD 200

typedef __attribute__((ext_vector_type(4))) float f32x4;
typedef __attribute__((ext_vector_type(8))) float f32x8;
typedef __attribute__((ext_vector_type(2))) _Float16 half2v;
typedef __attribute__((ext_vector_type(4))) _Float16 half4;
typedef __attribute__((ext_vector_type(8))) _Float16 half8;

static __device__ __forceinline__ int lbound(const int* a, int n, int v) {
  int lo = 0, hi = n;
  while (lo < hi) { int m = (lo + hi) >> 1; if (a[m] < v) lo = m + 1; else hi = m; }
  return lo;
}

// ---- prep: weights -> fp16 fragment order; emb -> fp16; zero deg ----
__global__ void k_prep(const float* __restrict__ w0, const float* __restrict__ w1,
                       const float* __restrict__ w2, const float* __restrict__ w3,
                       const float* __restrict__ mw1, const float* __restrict__ mw2,
                       const float* __restrict__ emb,
                       _Float16* __restrict__ cWf,   // [4][32*64*8]
                       _Float16* __restrict__ W1f,   // [352*64*8]
                       _Float16* __restrict__ W2f,   // [256*64*8]
                       _Float16* __restrict__ embh,  // [9*64*128]
                       int* __restrict__ deg) {
  int t = blockIdx.x * 256 + threadIdx.x;  // 0..65535
  if (t < N_NODES) deg[t] = 0;
  if (t < 8192) {
    int mat = t >> 11, r = t & 2047;
    int frag = r >> 6, lane = r & 63;
    int n0 = frag >> 2, kk = frag & 3;
    int n = n0 * 16 + (lane & 15);
    int kb = (lane >> 4) * 8 + kk * 32;
    const float* W = (mat == 0) ? w0 : (mat == 1) ? w1 : (mat == 2) ? w2 : w3;
    half8 o;
#pragma unroll
    for (int j = 0; j < 8; ++j) o[j] = (_Float16)W[(kb + j) * D + n];
    *(half8*)&cWf[((size_t)mat * 2048 + r) * 8] = o;
  } else if (t < 8192 + 22528) {
    int u = t - 8192;
    int frag = u >> 6, lane = u & 63;
    int n0 = frag / 11, kk = frag % 11;
    int n = n0 * 16 + (lane & 15);
    int kb = (lane >> 4) * 8 + kk * 32;
    half8 o;
#pragma unroll
    for (int j = 0; j < 8; ++j) {
      int k = kb + j;
      o[j] = (k < 328) ? (_Float16)mw1[k * 512 + n] : (_Float16)0.f;
    }
    *(half8*)&W1f[(size_t)u * 8] = o;
  } else if (t < 8192 + 22528 + 16384) {
    int u = t - 8192 - 22528;
    int frag = u >> 6, lane = u & 63;
    int n0 = frag >> 4, kk = frag & 15;
    int n = n0 * 16 + (lane & 15);
    int kb = (lane >> 4) * 8 + kk * 32;
    half8 o;
#pragma unroll
    for (int j = 0; j < 8; ++j) o[j] = (_Float16)mw2[(kb + j) * 256 + n];
    *(half8*)&W2f[(size_t)u * 8] = o;
  } else if (t < 8192 + 22528 + 16384 + 9216) {
    int u = t - 8192 - 22528 - 16384;  // 9216 half8 groups = 9*64*128 halves
    float4 v0 = *(const float4*)&emb[(size_t)u * 8];
    float4 v1 = *(const float4*)&emb[(size_t)u * 8 + 4];
    half8 o;
    o[0] = (_Float16)v0.x; o[1] = (_Float16)v0.y; o[2] = (_Float16)v0.z; o[3] = (_Float16)v0.w;
    o[4] = (_Float16)v1.x; o[5] = (_Float16)v1.y; o[6] = (_Float16)v1.z; o[7] = (_Float16)v1.w;
    *(half8*)&embh[(size_t)u * 8] = o;
  }
}

// fused: atom encoder (fp16 table) + degree count (rank captured) + edge pack
__global__ void k_atom_count(const int* __restrict__ xf, const _Float16* __restrict__ embh,
                             _Float16* __restrict__ x16,
                             const int* __restrict__ ei, const int* __restrict__ bondf,
                             int* __restrict__ deg,
                             int* __restrict__ dr,      // d | rank<<16
                             int* __restrict__ epack) {
  if (blockIdx.x < 6250) {
    int t = blockIdx.x * 256 + threadIdx.x;  // exactly 50000*32
    int node = t >> 5, c = (t & 31) << 2;
    int v[9];
#pragma unroll
    for (int f = 0; f < 9; ++f) v[f] = xf[node * 9 + f];
    f32x4 a = {0.f, 0.f, 0.f, 0.f};
#pragma unroll
    for (int f = 0; f < 9; ++f) {
      half4 e4 = *(const half4*)&embh[(size_t)(f * 64 + v[f]) * D + c];
      a += __builtin_convertvector(e4, f32x4);
    }
    half4 o;
    o.x = (_Float16)a[0]; o.y = (_Float16)a[1];
    o.z = (_Float16)a[2]; o.w = (_Float16)a[3];
    *(half4*)&x16[(size_t)node * D + c] = o;
  } else {
    int e = (blockIdx.x - 6250) * 256 + threadIdx.x;
    if (e < N_EDGES) {
      int d = ei[N_EDGES + e];
      int rank = atomicAdd(&deg[d], 1);  // rank among same-dst edges
      dr[e] = d | (rank << 16);
      int s = ei[e];
      int f0 = bondf[e * 3], f1 = bondf[e * 3 + 1], f2 = bondf[e * 3 + 2];
      epack[e] = s | (f0 << 16) | (f1 << 20) | (f2 << 24);
    }
  }
}

__global__ void k_scan_blocks(const int* __restrict__ deg, int* __restrict__ excl,
                              int* __restrict__ bsum) {
  __shared__ int sd[1024];
  int i = blockIdx.x * 1024 + threadIdx.x;
  int v = (i < N_NODES) ? deg[i] : 0;
  sd[threadIdx.x] = v;
  __syncthreads();
  for (int off = 1; off < 1024; off <<= 1) {
    int t = (threadIdx.x >= (unsigned)off) ? sd[threadIdx.x - off] : 0;
    __syncthreads();
    sd[threadIdx.x] += t;
    __syncthreads();
  }
  if (i < N_NODES) excl[i] = sd[threadIdx.x] - v;
  if (threadIdx.x == 1023) bsum[blockIdx.x] = sd[1023];
}

// add block-prefix; row_ptr[N] = E
__global__ void k_scan_add(int* __restrict__ row_ptr, const int* __restrict__ bsum) {
  int off = 0;
  for (int b = 0; b < blockIdx.x; ++b) off += bsum[b];
  int i = blockIdx.x * 1024 + threadIdx.x;
  if (i < N_NODES) row_ptr[i] += off;
  if (blockIdx.x == 0 && threadIdx.x == 0) row_ptr[N_NODES] = N_EDGES;
}

// atomic-free fill: pos = row_ptr[d] + rank (rank precomputed in k_atom_count)
__global__ void k_fill(const int* __restrict__ dr, const int* __restrict__ epack,
                       const int* __restrict__ row_ptr, int* __restrict__ csr1) {
  int e = blockIdx.x * 256 + threadIdx.x;
  if (e >= N_EDGES) return;
  int v = dr[e];
  int d = v & 0xFFFF, rank = v >> 16;
  csr1[row_ptr[d] + rank] = epack[e];
}

// out[i] = x[i] + sum_j relu(x[src] + bond_emb_sum)
// packed csr (src|f<<16), fp16 packed math, static strided node assignment.
__global__ __launch_bounds__(256) void k_agg(
    const _Float16* __restrict__ x16, const int* __restrict__ row_ptr,
    const int* __restrict__ csr1, const float* __restrict__ bemb,
    _Float16* __restrict__ out) {
  __shared__ half8 sB[48 * 16];  // 12 KB fp16 bond table
  for (int t = threadIdx.x; t < 768; t += blockDim.x) {
    float4 v0 = *(const float4*)&bemb[t * 8];
    float4 v1 = *(const float4*)&bemb[t * 8 + 4];
    half8 h;
    h[0] = (_Float16)v0.x; h[1] = (_Float16)v0.y; h[2] = (_Float16)v0.z; h[3] = (_Float16)v0.w;
    h[4] = (_Float16)v1.x; h[5] = (_Float16)v1.y; h[6] = (_Float16)v1.z; h[7] = (_Float16)v1.w;
    sB[t] = h;
  }
  __syncthreads();
  int lane = threadIdx.x & 63;
  int quad = lane >> 4;
  int l15 = lane & 15;
  int c8 = l15 * 8;
  int wid = blockIdx.x * (blockDim.x >> 6) + (threadIdx.x >> 6);
  int nw = gridDim.x * (blockDim.x >> 6);
  for (int i = wid; i < N_NODES; i += nw) {
    f32x8 ac[2];
    ac[0] = (f32x8)(0.f); ac[1] = (f32x8)(0.f);
    int e0 = row_ptr[i], e1 = row_ptr[i + 1];
    int j = e0 + quad;
#define EDGE(u, jj)                                                          \
    {                                                                        \
      unsigned ed = (unsigned)csr1[jj];                                      \
      half8 xr = *(const half8*)&x16[(size_t)(ed & 0xFFFF) * D + c8];        \
      unsigned p = ed >> 16;                                                 \
      half8 m16 = (xr + sB[(p & 15) * 16 + l15]) +                           \
                  (sB[256 + ((p >> 4) & 15) * 16 + l15] +                    \
                   sB[512 + (p >> 8) * 16 + l15]);                           \
      f32x8 m = __builtin_convertvector(m16, f32x8);                         \
      _Pragma("unroll")                                                      \
      for (int tt = 0; tt < 8; ++tt) ac[u][tt] += fmaxf(m[tt], 0.f);         \
    }
    for (; j + 4 < e1; j += 8) { EDGE(0, j) EDGE(1, j + 4) }
    for (; j < e1; j += 4) EDGE(0, j)
#undef EDGE
    f32x8 acc = ac[0] + ac[1];
#pragma unroll
    for (int tt = 0; tt < 8; ++tt) {
      acc[tt] += __shfl_xor(acc[tt], 16);
      acc[tt] += __shfl_xor(acc[tt], 32);
    }
    if (quad == 0) {
      half8 sr = *(const half8*)&x16[(size_t)i * D + c8];
      f32x8 o = __builtin_convertvector(sr, f32x8) + acc;
      *(half8*)&out[(size_t)i * D + c8] = __builtin_convertvector(o, half8);
    }
  }
}

// fused GINE nn: out = relu(A@W1+b1)@W2+b2 ; fp16 MFMA, W staged in LDS.
__global__ __launch_bounds__(256) void k_conv(
    const _Float16* __restrict__ A,
    const _Float16* __restrict__ W1f, const float* __restrict__ b1,
    const _Float16* __restrict__ W2f, const float* __restrict__ b2,
    _Float16* __restrict__ O16) {
  __shared__ _Float16 sW[2048 * 8];
  __shared__ _Float16 sI[128 * 136];
  int tid = threadIdx.x, w = tid >> 6, lane = tid & 63;
  int m0 = blockIdx.x * 128;
  int col16 = lane & 15, q = lane >> 4;
  for (int t = tid; t < 2048; t += 256)
    *(float4*)&sW[t * 8] = *(const float4*)&W1f[(size_t)t * 8];
  half8 afr[2][4];
#pragma unroll
  for (int f = 0; f < 2; ++f) {
    int row = m0 + w * 32 + f * 16 + col16;
    if (row >= N_NODES) row = N_NODES - 1;
    const _Float16* Ar = A + (size_t)row * D + q * 8;
#pragma unroll
    for (int kk = 0; kk < 4; ++kk) afr[f][kk] = *(const half8*)(Ar + kk * 32);
  }
  __syncthreads();
#pragma unroll
  for (int n0 = 0; n0 < 8; ++n0) {
    f32x4 a0 = {0.f, 0.f, 0.f, 0.f}, a1 = {0.f, 0.f, 0.f, 0.f};
#pragma unroll
    for (int kk = 0; kk < 4; ++kk) {
      half8 b = *(const half8*)&sW[((n0 * 4 + kk) * 64 + lane) * 8];
      a0 = __builtin_amdgcn_mfma_f32_16x16x32_f16(afr[0][kk], b, a0, 0, 0, 0);
      a1 = __builtin_amdgcn_mfma_f32_16x16x32_f16(afr[1][kk], b, a1, 0, 0, 0);
    }
    float bb = b1[n0 * 16 + col16];
#pragma unroll
    for (int r = 0; r < 4; ++r) {
      sI[(w * 32 + q * 4 + r) * 136 + n0 * 16 + col16] = (_Float16)fmaxf(a0[r] + bb, 0.f);
      sI[(w * 32 + 16 + q * 4 + r) * 136 + n0 * 16 + col16] = (_Float16)fmaxf(a1[r] + bb, 0.f);
    }
  }
  __syncthreads();
  for (int t = tid; t < 2048; t += 256)
    *(float4*)&sW[t * 8] = *(const float4*)&W2f[(size_t)t * 8];
  half8 a2[2][4];
#pragma unroll
  for (int f = 0; f < 2; ++f) {
    const _Float16* tr = &sI[(w * 32 + f * 16 + col16) * 136 + q * 8];
#pragma unroll
    for (int kk = 0; kk < 4; ++kk) a2[f][kk] = *(const half8*)(tr + kk * 32);
  }
  __syncthreads();
#pragma unroll
  for (int n0 = 0; n0 < 8; ++n0) {
    f32x4 a0 = {0.f, 0.f, 0.f, 0.f}, a1 = {0.f, 0.f, 0.f, 0.f};
#pragma unroll
    for (int kk = 0; kk < 4; ++kk) {
      half8 b = *(const half8*)&sW[((n0 * 4 + kk) * 64 + lane) * 8];
      a0 = __builtin_amdgcn_mfma_f32_16x16x32_f16(a2[0][kk], b, a0, 0, 0, 0);
      a1 = __builtin_amdgcn_mfma_f32_16x16x32_f16(a2[1][kk], b, a1, 0, 0, 0);
    }
    int col = n0 * 16 + col16;
    float bb = b2[col];
#pragma unroll
    for (int r = 0; r < 4; ++r) {
      int r0 = m0 + w * 32 + q * 4 + r;
      int r1 = r0 + 16;
      if (r0 < N_NODES) O16[(size_t)r0 * D + col] = (_Float16)(a0[r] + bb);
      if (r1 < N_NODES) O16[(size_t)r1 * D + col] = (_Float16)(a1[r] + bb);
    }
  }
}

// mean-pool per graph -> hcat16[G][352]; also out[g] = b3 (mlp23 atomics add onto it)
__global__ __launch_bounds__(256) void k_pool(
    const _Float16* __restrict__ x, const int* __restrict__ batch,
    const float* __restrict__ rdkit, _Float16* __restrict__ hcat,
    const float* __restrict__ B3, float* __restrict__ out) {
  int g = blockIdx.x * 4 + (threadIdx.x >> 6);
  if (g >= N_GRAPH) return;
  int lane = threadIdx.x & 63;
  int half_ = lane >> 5;
  int c4 = (lane & 31) * 4;
  int lo = lbound(batch, N_NODES, g);
  int hi = lbound(batch, N_NODES, g + 1);
  f32x4 a = {0.f, 0.f, 0.f, 0.f};
  for (int i = lo + half_; i < hi; i += 2) {
    half4 v = *(const half4*)&x[(size_t)i * D + c4];
    a += __builtin_convertvector(v, f32x4);
  }
#pragma unroll
  for (int t = 0; t < 4; ++t) a[t] += __shfl_xor(a[t], 32);
  float inv = 1.f / fmaxf((float)(hi - lo), 1.f);
  if (half_ == 0) {
    half4 o;
    o.x = (_Float16)(a[0] * inv); o.y = (_Float16)(a[1] * inv);
    o.z = (_Float16)(a[2] * inv); o.w = (_Float16)(a[3] * inv);
    *(half4*)&hcat[(size_t)g * 352 + c4] = o;
  }
  for (int r = lane; r < RD; r += 64)
    hcat[(size_t)g * 352 + D + r] = (_Float16)rdkit[(size_t)g * RD + r];
  if (lane < 24) hcat[(size_t)g * 352 + 328 + lane] = (_Float16)0.f;
  if (lane == 0) out[g] = B3[0];
}

// h1 = relu(hcat16 @ W1 + b1); wave = (mtile, 16-col group) -> 2048 waves / 512 blocks
__global__ __launch_bounds__(256) void k_mlp1(
    const _Float16* __restrict__ A, const _Float16* __restrict__ W1f,
    const float* __restrict__ B, _Float16* __restrict__ O) {
  int w = threadIdx.x >> 6, lane = threadIdx.x & 63;
  int gid = blockIdx.x * 4 + w;  // 0..2047
  int mt = gid >> 5, n0 = gid & 31;
  int col16 = lane & 15, q = lane >> 4;
  const _Float16* Ar = A + (size_t)(mt * 16 + col16) * 352 + q * 8;
  f32x4 acc = {0.f, 0.f, 0.f, 0.f};
#pragma unroll
  for (int kk = 0; kk < 11; ++kk) {
    half8 a = *(const half8*)(Ar + kk * 32);
    half8 b = *(const half8*)&W1f[(size_t)((n0 * 11 + kk) * 64 + lane) * 8];
    acc = __builtin_amdgcn_mfma_f32_16x16x32_f16(a, b, acc, 0, 0, 0);
  }
  int col = n0 * 16 + col16;
  float bb = B[col];
#pragma unroll
  for (int r = 0; r < 4; ++r) {
    int row = mt * 16 + q * 4 + r;
    O[(size_t)row * 512 + col] = (_Float16)fmaxf(acc[r] + bb, 0.f);
  }
}

// out[g] += sum_cols relu(h1@W2+b2)*w3 ; wave = (mtile, 16-col group) -> 1024 waves / 256 blocks
__global__ __launch_bounds__(256) void k_mlp23(
    const _Float16* __restrict__ A, const _Float16* __restrict__ W2f,
    const float* __restrict__ B2, const float* __restrict__ W3,
    float* __restrict__ out) {
  int w = threadIdx.x >> 6, lane = threadIdx.x & 63;
  int gid = blockIdx.x * 4 + w;  // 0..1023
  int mt = gid >> 4, n0 = gid & 15;
  int col16 = lane & 15, q = lane >> 4;
  const _Float16* Ar = A + (size_t)(mt * 16 + col16) * 512 + q * 8;
  f32x4 acc = {0.f, 0.f, 0.f, 0.f};
#pragma unroll
  for (int kk = 0; kk < 16; ++kk) {
    half8 a = *(const half8*)(Ar + kk * 32);
    half8 b = *(const half8*)&W2f[(size_t)((n0 * 16 + kk) * 64 + lane) * 8];
    acc = __builtin_amdgcn_mfma_f32_16x16x32_f16(a, b, acc, 0, 0, 0);
  }
  int col = n0 * 16 + col16;
  float bb = B2[col], w3 = W3[col];
  float p[4];
#pragma unroll
  for (int r = 0; r < 4; ++r) p[r] = fmaxf(acc[r] + bb, 0.f) * w3;
#pragma unroll
  for (int r = 0; r < 4; ++r) {
    p[r] += __shfl_xor(p[r], 1);
    p[r] += __shfl_xor(p[r], 2);
    p[r] += __shfl_xor(p[r], 4);
    p[r] += __shfl_xor(p[r], 8);
  }
  if (col16 == 0) {
#pragma unroll
    for (int r = 0; r < 4; ++r)
      atomicAdd(&out[mt * 16 + q * 4 + r], p[r]);
  }
}

extern "C" void kernel_launch(void* const* d_in, const int* in_sizes, int n_in,
                              void* d_out, int out_size, void* d_ws, size_t ws_size,
                              hipStream_t stream) {
  const int* x_feat = (const int*)d_in[0];
  const int* ei = (const int*)d_in[1];
  const int* bondf = (const int*)d_in[2];
  const int* batch = (const int*)d_in[3];
  const float* rdkit = (const float*)d_in[4];
  const float* atom_emb = (const float*)d_in[5];
  const float* bond_emb = (const float*)d_in[6];
  const float* c1w1 = (const float*)d_in[7];
  const float* c1b1 = (const float*)d_in[8];
  const float* c1w2 = (const float*)d_in[9];
  const float* c1b2 = (const float*)d_in[10];
  const float* c2w1 = (const float*)d_in[11];
  const float* c2b1 = (const float*)d_in[12];
  const float* c2w2 = (const float*)d_in[13];
  const float* c2b2 = (const float*)d_in[14];
  const float* mw1 = (const float*)d_in[15];
  const float* mb1 = (const float*)d_in[16];
  const float* mw2 = (const float*)d_in[17];
  const float* mb2 = (const float*)d_in[18];
  const float* mw3 = (const float*)d_in[19];
  const float* mb3 = (const float*)d_in[20];
  float* out = (float*)d_out;

  char* ws = (char*)d_ws;
  size_t off = 0;
  auto alloc = [&](size_t bytes) {
    void* p = ws + off;
    off += (bytes + 255) & ~(size_t)255;
    return p;
  };
  _Float16* x16a = (_Float16*)alloc((size_t)N_NODES * D * 2);
  _Float16* x16b = (_Float16*)alloc((size_t)N_NODES * D * 2);
  _Float16* h16 = (_Float16*)alloc((size_t)N_NODES * D * 2);
  _Float16* x2_16 = (_Float16*)alloc((size_t)N_NODES * D * 2);
  int* deg = (int*)alloc((size_t)N_NODES * 4);
  int* row_ptr = (int*)alloc((size_t)(N_NODES + 1) * 4);
  int* bsum = (int*)alloc(64 * 4);
  int* csr1 = (int*)alloc((size_t)N_EDGES * 4);
  int* dr = (int*)alloc((size_t)N_EDGES * 4);
  int* epack = (int*)alloc((size_t)N_EDGES * 4);
  _Float16* hcat16 = (_Float16*)alloc((size_t)N_GRAPH * 352 * 2);
  _Float16* h1buf = (_Float16*)alloc((size_t)N_GRAPH * 512 * 2);
  _Float16* cWf = (_Float16*)alloc((size_t)4 * 2048 * 8 * 2);
  _Float16* W1f = (_Float16*)alloc((size_t)352 * 64 * 8 * 2);
  _Float16* W2f = (_Float16*)alloc((size_t)256 * 64 * 8 * 2);
  _Float16* embh = (_Float16*)alloc((size_t)9 * 64 * D * 2);

  k_prep<<<256, 256, 0, stream>>>(c1w1, c1w2, c2w1, c2w2, mw1, mw2, atom_emb,
                                  cWf, W1f, W2f, embh, deg);
  k_atom_count<<<6250 + 2500, 256, 0, stream>>>(x_feat, embh, x16a,
                                                ei, bondf, deg, dr, epack);

  int nb = (N_NODES + 1023) / 1024;
  k_scan_blocks<<<nb, 1024, 0, stream>>>(deg, row_ptr, bsum);
  k_scan_add<<<nb, 1024, 0, stream>>>(row_ptr, bsum);
  k_fill<<<(N_EDGES + 255) / 256, 256, 0, stream>>>(dr, epack, row_ptr, csr1);

  int ctiles = (N_NODES + 127) / 128;  // 391
  // conv1
  k_agg<<<2048, 256, 0, stream>>>(x16a, row_ptr, csr1, bond_emb, h16);
  k_conv<<<ctiles, 256, 0, stream>>>(h16, cWf + 0 * 16384, c1b1,
                                     cWf + 1 * 16384, c1b2, x16b);
  // conv2
  k_agg<<<2048, 256, 0, stream>>>(x16b, row_ptr, csr1, bond_emb, h16);
  k_conv<<<ctiles, 256, 0, stream>>>(h16, cWf + 2 * 16384, c2b1,
                                     cWf + 3 * 16384, c2b2, x2_16);

  // pool (also inits out = b3) + high-parallelism head
  k_pool<<<N_GRAPH / 4, 256, 0, stream>>>(x2_16, batch, rdkit, hcat16, mb3, out);
  k_mlp1<<<512, 256, 0, stream>>>(hcat16, W1f, mb1, h1buf);
  k_mlp23<<<256, 256, 0, stream>>>(h1buf, W2f, mb2, mw3, out);

  (void)in_sizes; (void)n_in; (void)out_size; (void)ws_size;
}